// Round 6
// baseline (458.865 us; speedup 1.0000x reference)
//
#include <hip/hip_runtime.h>
#include <math.h>

typedef __bf16 bf16x8 __attribute__((ext_vector_type(8)));
typedef __bf16 bf16x4 __attribute__((ext_vector_type(4)));
typedef float  f32x4  __attribute__((ext_vector_type(4)));
typedef float  f32x2  __attribute__((ext_vector_type(2)));
typedef unsigned int u32;

__device__ __forceinline__ float silu_f(float x){ return x / (1.f + __expf(-x)); }
__device__ __forceinline__ float sigm_f(float x){ return 1.f / (1.f + __expf(-x)); }

__device__ __forceinline__ float ntld_f(const float* p){
  return __builtin_nontemporal_load(p);
}
__device__ __forceinline__ float ntbf(const __bf16* p){
  unsigned short us = __builtin_nontemporal_load((const unsigned short*)p);
  union { unsigned u; float f; } cv; cv.u = ((unsigned)us) << 16;
  return cv.f;
}
__device__ __forceinline__ void nt_store_b4(__bf16* p, bf16x4 v){
  unsigned long long u;
  __builtin_memcpy(&u, &v, 8);
  __builtin_nontemporal_store(u, (unsigned long long*)p);
}
__device__ __forceinline__ void nt_store_f(float* p, float v){
  __builtin_nontemporal_store(v, p);
}

// async global->LDS, 16B per lane; dest = (uniform base) + lane*16
__device__ __forceinline__ void gl16(const void* g, void* l){
  __builtin_amdgcn_global_load_lds(
      (const __attribute__((address_space(1))) u32*)g,
      (__attribute__((address_space(3))) u32*)l, 16, 0, 0);
}

__device__ __forceinline__ f32x2 b4lo(bf16x4 v){ f32x2 r; r[0]=(float)v[0]; r[1]=(float)v[1]; return r; }
__device__ __forceinline__ f32x2 b4hi(bf16x4 v){ f32x2 r; r[0]=(float)v[2]; r[1]=(float)v[3]; return r; }

// Block ranges: [0,nbPrep) W2->bf16 transpose; [nbPrep,+nbHist) dst histogram;
// rest: per-node attention vectors kv[n]=Wk@(nf@Wq+bq), c[n]=(nf@Wq+bq).bk
__global__ void __launch_bounds__(256) k_setup(const float* __restrict__ W2,
    __bf16* __restrict__ W2t, const int* __restrict__ ei, int* __restrict__ cnt,
    const float* __restrict__ nf, const float* __restrict__ Wq,
    const float* __restrict__ bq, const float* __restrict__ Wk,
    const float* __restrict__ bk, float* __restrict__ kvt, float* __restrict__ carr,
    int nbPrep, int nbHist, int N, int E){
  int b = blockIdx.x, t = threadIdx.x;
  if (b < nbPrep){
    int gid = b*256 + t;   // 163840 total
    int h = gid / 2560;
    int col = gid - h*2560;
    W2t[(size_t)(h>>5)*81920 + col*32 + (h&31)] = (__bf16)ntld_f(&W2[gid]);
    return;
  }
  if (b < nbPrep + nbHist){
    int e = (b - nbPrep)*256 + t;
    if (e < E) atomicAdd(&cnt[ei[E+e]], 1);
    return;
  }
  // kv/c blocks: 64 nodes each
  __shared__ float M[32][33];
  __shared__ float mb[32];
  __shared__ float nfl[64][33];
  __shared__ float bqbk_s;
  const int n0 = (b - nbPrep - nbHist)*64;
  for (int idx = t; idx < 1024; idx += 256){
    int s = idx >> 5, i = idx & 31;
    float acc = 0.f;
    #pragma unroll
    for (int j = 0; j < 8; ++j) acc += Wq[s*8+j]*Wk[i*8+j];
    M[s][i] = acc;
  }
  if (t < 32){
    float acc = 0.f;
    #pragma unroll
    for (int j = 0; j < 8; ++j) acc += Wq[t*8+j]*bk[j];
    mb[t] = acc;
  }
  if (t == 0){
    float acc = 0.f;
    #pragma unroll
    for (int j = 0; j < 8; ++j) acc += bq[j]*bk[j];
    bqbk_s = acc;
  }
  for (int idx = t; idx < 2048; idx += 256){
    int nl = idx >> 5, s = idx & 31;
    int n = n0 + nl;
    nfl[nl][s] = (n < N) ? nf[(size_t)n*80 + s] : 0.f;
  }
  __syncthreads();
  for (int idx = t; idx < 2048; idx += 256){
    int nl = idx >> 5, i = idx & 31;
    int n = n0 + nl;
    if (n < N){
      float acc = 0.f;
      #pragma unroll 8
      for (int s = 0; s < 32; ++s) acc += nfl[nl][s]*M[s][i];
      kvt[(size_t)n*32 + i] = acc;
    }
  }
  if (t < 64){
    int n = n0 + t;
    if (n < N){
      float acc = bqbk_s;
      #pragma unroll 8
      for (int s = 0; s < 32; ++s) acc += nfl[t][s]*mb[s];
      carr[n] = acc;
    }
  }
}

__global__ void __launch_bounds__(1024) k_scan(const int* __restrict__ cnt,
    int* __restrict__ cursor, float* __restrict__ bnacc, int N, int E){
  __shared__ int part[1024];
  int t = threadIdx.x;
  if (t < 80) bnacc[t] = 0.f;
  int chunk = (N + 1023) >> 10;
  int lo = t*chunk, hi = min(lo+chunk, N);
  int s = 0;
  for (int i = lo; i < hi; ++i) s += cnt[i];
  part[t] = s;
  __syncthreads();
  for (int off = 1; off < 1024; off <<= 1){
    int v = (t >= off) ? part[t-off] : 0;
    __syncthreads();
    part[t] += v;
    __syncthreads();
  }
  int base = (t == 0) ? 0 : part[t-1];
  for (int i = lo; i < hi; ++i){
    cursor[i] = base;
    base += cnt[i];
  }
}

// issue both halves of panel IT into ring slot SLOT (async, 0 VGPR cost).
// lgkmcnt(0) first: the slot's prior ds_reads must have retired to VGPRs.
#define ISSUE(IT, SLOT) do {                                                  \
    asm volatile("s_waitcnt lgkmcnt(0)" ::: "memory");                        \
    const char* g0_ = (const char*)(srcB + (size_t)(IT)*512);                 \
    gl16(g0_,          (char*)sb + (SLOT)*2048);                              \
    gl16(g0_ + 163840, (char*)sb + (SLOT)*2048 + 1024);                       \
  } while(0)

// one scalar-column iteration out of ring slot SLOT; waits vmcnt(VMC)
#define SSTEP(SLOT, VMC, DOI) do {                                            \
    asm volatile("s_waitcnt vmcnt(" #VMC ")" ::: "memory");                   \
    const __bf16* pb_ = sb + (SLOT)*1024;                                     \
    bf16x8 B0_ = *(const bf16x8*)(pb_ + lane*8);                              \
    bf16x8 B1_ = *(const bf16x8*)(pb_ + 512 + lane*8);                        \
    f32x4 d0_ = {0.f,0.f,0.f,0.f}, d1_ = {0.f,0.f,0.f,0.f};                   \
    d0_ = __builtin_amdgcn_mfma_f32_16x16x32_bf16(afrA0, B0_, d0_, 0,0,0);    \
    d1_ = __builtin_amdgcn_mfma_f32_16x16x32_bf16(afrB0, B0_, d1_, 0,0,0);    \
    d0_ = __builtin_amdgcn_mfma_f32_16x16x32_bf16(afrA1, B1_, d0_, 0,0,0);    \
    d1_ = __builtin_amdgcn_mfma_f32_16x16x32_bf16(afrB1, B1_, d1_, 0,0,0);    \
    if (DOI) ISSUE(it+4, SLOT);                                               \
    const float bias_ = b2l[it*16 + nlo];                                     \
    f32x2 bb_; bb_[0] = bias_; bb_[1] = bias_;                                \
    f32x2 d0lo_ = __builtin_shufflevector(d0_,d0_,0,1) + bb_;                 \
    f32x2 d0hi_ = __builtin_shufflevector(d0_,d0_,2,3) + bb_;                 \
    f32x2 d1lo_ = __builtin_shufflevector(d1_,d1_,0,1) + bb_;                 \
    f32x2 d1hi_ = __builtin_shufflevector(d1_,d1_,2,3) + bb_;                 \
    const int r_ = it >> 1;                                                   \
    bf16x4 cA_ = *(const bf16x4*)&cABt[r_][quad*4];                           \
    bf16x4 cB_ = *(const bf16x4*)&cABt[r_][16+quad*4];                        \
    if ((SLOT)&1){                                                            \
      sA1lo += b4lo(cA_)*d0lo_; sA1hi += b4hi(cA_)*d0hi_;                     \
      sB1lo += b4lo(cB_)*d1lo_; sB1hi += b4hi(cB_)*d1hi_;                     \
    } else {                                                                  \
      sA0lo += b4lo(cA_)*d0lo_; sA0hi += b4hi(cA_)*d0hi_;                     \
      sB0lo += b4lo(cB_)*d1lo_; sB0hi += b4hi(cB_)*d1hi_;                     \
    }                                                                         \
    ++it;                                                                     \
  } while(0)

// one vector-column iteration
#define VSTEP(SLOT, VMC, DOI) do {                                            \
    asm volatile("s_waitcnt vmcnt(" #VMC ")" ::: "memory");                   \
    const __bf16* pb_ = sb + (SLOT)*1024;                                     \
    bf16x8 B0_ = *(const bf16x8*)(pb_ + lane*8);                              \
    bf16x8 B1_ = *(const bf16x8*)(pb_ + 512 + lane*8);                        \
    f32x4 d0_ = {0.f,0.f,0.f,0.f}, d1_ = {0.f,0.f,0.f,0.f};                   \
    d0_ = __builtin_amdgcn_mfma_f32_16x16x32_bf16(afrA0, B0_, d0_, 0,0,0);    \
    d1_ = __builtin_amdgcn_mfma_f32_16x16x32_bf16(afrB0, B0_, d1_, 0,0,0);    \
    d0_ = __builtin_amdgcn_mfma_f32_16x16x32_bf16(afrA1, B1_, d0_, 0,0,0);    \
    d1_ = __builtin_amdgcn_mfma_f32_16x16x32_bf16(afrB1, B1_, d1_, 0,0,0);    \
    if (DOI) ISSUE(it+4, SLOT);                                               \
    const float bias_ = b2l[it*16 + nlo];                                     \
    f32x2 bb_; bb_[0] = bias_; bb_[1] = bias_;                                \
    f32x2 d0lo_ = __builtin_shufflevector(d0_,d0_,0,1) + bb_;                 \
    f32x2 d0hi_ = __builtin_shufflevector(d0_,d0_,2,3) + bb_;                 \
    f32x2 d1lo_ = __builtin_shufflevector(d1_,d1_,0,1) + bb_;                 \
    f32x2 d1hi_ = __builtin_shufflevector(d1_,d1_,2,3) + bb_;                 \
    const int r_ = it - 96;                                                   \
    bf16x4 qA0_ = *(const bf16x4*)&cVt[r_][0][quad*4];                        \
    bf16x4 qA1_ = *(const bf16x4*)&cVt[r_][1][quad*4];                        \
    bf16x4 qA2_ = *(const bf16x4*)&cVt[r_][2][quad*4];                        \
    bf16x4 qB0_ = *(const bf16x4*)&cVt[r_][0][16+quad*4];                     \
    bf16x4 qB1_ = *(const bf16x4*)&cVt[r_][1][16+quad*4];                     \
    bf16x4 qB2_ = *(const bf16x4*)&cVt[r_][2][16+quad*4];                     \
    vA0lo += b4lo(qA0_)*d0lo_; vA0hi += b4hi(qA0_)*d0hi_;                     \
    vA1lo += b4lo(qA1_)*d0lo_; vA1hi += b4hi(qA1_)*d0hi_;                     \
    vA2lo += b4lo(qA2_)*d0lo_; vA2hi += b4hi(qA2_)*d0hi_;                     \
    vB0lo += b4lo(qB0_)*d1lo_; vB0hi += b4hi(qB0_)*d1hi_;                     \
    vB1lo += b4lo(qB1_)*d1lo_; vB1hi += b4hi(qB1_)*d1hi_;                     \
    vB2lo += b4lo(qB2_)*d1lo_; vB2hi += b4hi(qB2_)*d1hi_;                     \
    ++it;                                                                     \
  } while(0)

// 32 edges / 256-thread block, 2 M-tiles per wave. Wave-specialized
// contiguous 40-it ranges; B-panels streamed via per-wave 4-slot LDS ring
// filled by async global_load_lds (0 VGPR, counted vmcnt self-sync, no
// barriers in loop). bf16 coef tables, b2 in LDS. LDS ~75 KB -> 2 blk/CU.
__global__ void __launch_bounds__(256, 2) k_edge(
    const float* __restrict__ nf, const int* __restrict__ ei,
    const float* __restrict__ sh, const float* __restrict__ radial,
    const float* __restrict__ env,
    const float* __restrict__ W1, const float* __restrict__ b1,
    const __bf16* __restrict__ W2t, const float* __restrict__ b2,
    const float* __restrict__ kvt, const float* __restrict__ carr,
    int* __restrict__ cursor,
    __bf16* __restrict__ msgs, float* __restrict__ logits_s, int E)
{
  __shared__ __align__(16) __bf16 ring[4][4][2][512];    // 32768 B
  __shared__ __bf16 u_lds[32][72];                       // 4608 B
  __shared__ __align__(16) float uniA[2688];             // featT[80][33] <-> macc[32][84]
  __shared__ __align__(8)  __bf16 cABt[48][32];          // 3072 B
  __shared__ __align__(16) char uniB[12288];             // w1l f32[1024] <-> cVt bf16[64][3][32]
  __shared__ __align__(16) float b2l[2560];              // 10240 B
  __shared__ float shlT[4][33];
  __shared__ float radl[32][17];
  __shared__ float b1l[64];
  __shared__ int   src_l[32], dst_l[32], perm_l[32];

  float (*featT)[33] = (float(*)[33])uniA;
  float (*macc)[84]  = (float(*)[84])uniA;
  float* w1l = (float*)uniB;
  __bf16 (*cVt)[3][32] = (__bf16(*)[3][32])uniB;

  const int t = threadIdx.x;
  const int e0 = blockIdx.x*32;
  const int lane = t & 63;
  const int wv   = __builtin_amdgcn_readfirstlane(t >> 6);   // wave-uniform
  const int quad = lane >> 4;
  const int nlo  = lane & 15;

  const __bf16* srcB = W2t + (size_t)nlo*32 + (size_t)quad*8;
  const __bf16* sb   = &ring[wv][0][0][0];
  const int itB = wv*40;

  // ---- prologue: issue first 4 panel-pairs of this wave's range now;
  // latency hides behind the staging phases below.
  ISSUE(itB+0, 0); ISSUE(itB+1, 1); ISSUE(itB+2, 2); ISSUE(itB+3, 3);

  // ---- stage 1: indices + fused CSR placement, sh, radial, W1, b1, b2
  if (t < 32){
    int ee = e0 + t;
    if (ee < E){
      int sn = ei[ee], dn = ei[E+ee];
      src_l[t] = sn; dst_l[t] = dn;
      perm_l[t] = atomicAdd(&cursor[dn], 1);
    } else {
      int ec = E-1;
      src_l[t] = ei[ec]; dst_l[t] = ei[E+ec]; perm_l[t] = 0;
    }
  }
  if (t >= 64 && t < 192){
    int i = t-64; int e = i>>2, c = i&3;
    int ec = min(e0+e, E-1);
    shlT[c][e] = ntld_f(&sh[(size_t)ec*4+c]);
  }
  if (t >= 192) b1l[t-192] = b1[t-192];
  for (int i = t; i < 512; i += 256){
    int e = i>>4, r = i&15;
    int ec = min(e0+e, E-1);
    radl[e][r] = ntld_f(&radial[(size_t)ec*16+r]);
  }
  *(float4*)&w1l[t*4] = ((const float4*)W1)[t];
  for (int i = t; i < 640; i += 256)
    ((float4*)b2l)[i] = ((const float4*)b2)[i];
  __syncthreads();

  // ---- stage 2: featT (transposed) + u = silu(radial@W1+b1) -> bf16
  for (int i = t; i < 2560; i += 256){
    int e = i / 80, idx = i - e*80;
    featT[idx][e] = nf[(size_t)src_l[e]*80 + idx];
  }
  for (int i = t; i < 2048; i += 256){
    int e = i & 31, h = i >> 5;
    float acc = b1l[h];
    #pragma unroll
    for (int r = 0; r < 16; ++r) acc += radl[e][r]*w1l[r*64+h];
    u_lds[e][h] = (__bf16)silu_f(acc);
  }
  __syncthreads();

  const float inv_s3 = 0.57735026918962576f;
  const float inv_s2 = 0.70710678118654752f;
  const float a0 = 0.14433756729740643f;  // 1/sqrt(48)
  const float a1 = 0.125f;                // 1/sqrt(64)

  // ---- stage 3: coefficients (bf16, transposed); cVt overwrites dead w1l
  for (int i = t; i < 1536; i += 256){
    int r = i >> 5, e = i & 31;
    float val;
    if (r < 32) val = a0 * shlT[0][e] * featT[r][e];
    else {
      int v = r - 32;
      float dot = (featT[32+v*3][e]*shlT[1][e] + featT[33+v*3][e]*shlT[2][e]
                 + featT[34+v*3][e]*shlT[3][e]) * inv_s3;
      val = a0 * dot;
    }
    cABt[r][e] = (__bf16)val;
  }
  for (int i = t; i < 6144; i += 256){
    int e = i & 31, r = (i >> 5) & 63, c = i >> 11;
    float val;
    if (r < 32) val = a1 * shlT[1+c][e] * featT[r][e];
    else if (r < 48){
      int v = r - 32;
      val = a1 * shlT[0][e] * featT[32+v*3+c][e];
    } else {
      int v = r - 48;
      int c1 = c+1; if (c1 > 2) c1 -= 3;
      int c2 = c+2; if (c2 > 2) c2 -= 3;
      val = a1 * inv_s2 * (featT[32+v*3+c1][e]*shlT[1+c2][e]
                         - featT[32+v*3+c2][e]*shlT[1+c1][e]);
    }
    cVt[r][c][e] = (__bf16)val;
  }
  __syncthreads();

  // ---- zero macc (aliases featT, now dead)
  for (int i = t; i < 2688; i += 256) uniA[i] = 0.f;
  __syncthreads();

  // ---- stage 4: per-wave ring-pipelined MFMA loop (no barriers inside)
  const bf16x8 afrA0 = *(const bf16x8*)&u_lds[nlo][quad*8];
  const bf16x8 afrA1 = *(const bf16x8*)&u_lds[nlo][32 + quad*8];
  const bf16x8 afrB0 = *(const bf16x8*)&u_lds[16+nlo][quad*8];
  const bf16x8 afrB1 = *(const bf16x8*)&u_lds[16+nlo][32 + quad*8];

  f32x2 sA0lo={0,0}, sA0hi={0,0}, sA1lo={0,0}, sA1hi={0,0};
  f32x2 sB0lo={0,0}, sB0hi={0,0}, sB1lo={0,0}, sB1hi={0,0};
  f32x2 vA0lo={0,0}, vA0hi={0,0}, vA1lo={0,0}, vA1hi={0,0}, vA2lo={0,0}, vA2hi={0,0};
  f32x2 vB0lo={0,0}, vB0hi={0,0}, vB1lo={0,0}, vB1hi={0,0}, vB2lo={0,0}, vB2hi={0,0};

  int it = itB;
  if (wv < 2){
    for (int c = 0; c < 9; ++c){
      SSTEP(0,6,1); SSTEP(1,6,1); SSTEP(2,6,1); SSTEP(3,6,1);
    }
    SSTEP(0,6,0); SSTEP(1,4,0); SSTEP(2,2,0); SSTEP(3,0,0);
  } else if (wv == 2){
    for (int c = 0; c < 4; ++c){
      SSTEP(0,6,1); SSTEP(1,6,1); SSTEP(2,6,1); SSTEP(3,6,1);
    }
    for (int c = 0; c < 5; ++c){
      VSTEP(0,6,1); VSTEP(1,6,1); VSTEP(2,6,1); VSTEP(3,6,1);
    }
    VSTEP(0,6,0); VSTEP(1,4,0); VSTEP(2,2,0); VSTEP(3,0,0);
  } else {
    for (int c = 0; c < 9; ++c){
      VSTEP(0,6,1); VSTEP(1,6,1); VSTEP(2,6,1); VSTEP(3,6,1);
    }
    VSTEP(0,6,0); VSTEP(1,4,0); VSTEP(2,2,0); VSTEP(3,0,0);
  }

  // ---- reduce into macc (LDS atomics; waves 0-2 scalar, waves 2-3 vector)
  if (wv < 3){
    atomicAdd(&macc[quad*4+0][nlo],    sA0lo[0]);
    atomicAdd(&macc[quad*4+1][nlo],    sA0lo[1]);
    atomicAdd(&macc[quad*4+2][nlo],    sA0hi[0]);
    atomicAdd(&macc[quad*4+3][nlo],    sA0hi[1]);
    atomicAdd(&macc[quad*4+0][16+nlo], sA1lo[0]);
    atomicAdd(&macc[quad*4+1][16+nlo], sA1lo[1]);
    atomicAdd(&macc[quad*4+2][16+nlo], sA1hi[0]);
    atomicAdd(&macc[quad*4+3][16+nlo], sA1hi[1]);
    atomicAdd(&macc[16+quad*4+0][nlo],    sB0lo[0]);
    atomicAdd(&macc[16+quad*4+1][nlo],    sB0lo[1]);
    atomicAdd(&macc[16+quad*4+2][nlo],    sB0hi[0]);
    atomicAdd(&macc[16+quad*4+3][nlo],    sB0hi[1]);
    atomicAdd(&macc[16+quad*4+0][16+nlo], sB1lo[0]);
    atomicAdd(&macc[16+quad*4+1][16+nlo], sB1lo[1]);
    atomicAdd(&macc[16+quad*4+2][16+nlo], sB1hi[0]);
    atomicAdd(&macc[16+quad*4+3][16+nlo], sB1hi[1]);
  }
  if (wv >= 2){
    atomicAdd(&macc[quad*4+0][32+nlo*3+0], vA0lo[0]);
    atomicAdd(&macc[quad*4+1][32+nlo*3+0], vA0lo[1]);
    atomicAdd(&macc[quad*4+2][32+nlo*3+0], vA0hi[0]);
    atomicAdd(&macc[quad*4+3][32+nlo*3+0], vA0hi[1]);
    atomicAdd(&macc[quad*4+0][32+nlo*3+1], vA1lo[0]);
    atomicAdd(&macc[quad*4+1][32+nlo*3+1], vA1lo[1]);
    atomicAdd(&macc[quad*4+2][32+nlo*3+1], vA1hi[0]);
    atomicAdd(&macc[quad*4+3][32+nlo*3+1], vA1hi[1]);
    atomicAdd(&macc[quad*4+0][32+nlo*3+2], vA2lo[0]);
    atomicAdd(&macc[quad*4+1][32+nlo*3+2], vA2lo[1]);
    atomicAdd(&macc[quad*4+2][32+nlo*3+2], vA2hi[0]);
    atomicAdd(&macc[quad*4+3][32+nlo*3+2], vA2hi[1]);
    atomicAdd(&macc[16+quad*4+0][32+nlo*3+0], vB0lo[0]);
    atomicAdd(&macc[16+quad*4+1][32+nlo*3+0], vB0lo[1]);
    atomicAdd(&macc[16+quad*4+2][32+nlo*3+0], vB0hi[0]);
    atomicAdd(&macc[16+quad*4+3][32+nlo*3+0], vB0hi[1]);
    atomicAdd(&macc[16+quad*4+0][32+nlo*3+1], vB1lo[0]);
    atomicAdd(&macc[16+quad*4+1][32+nlo*3+1], vB1lo[1]);
    atomicAdd(&macc[16+quad*4+2][32+nlo*3+1], vB1hi[0]);
    atomicAdd(&macc[16+quad*4+3][32+nlo*3+1], vB1hi[1]);
    atomicAdd(&macc[16+quad*4+0][32+nlo*3+2], vB2lo[0]);
    atomicAdd(&macc[16+quad*4+1][32+nlo*3+2], vB2lo[1]);
    atomicAdd(&macc[16+quad*4+2][32+nlo*3+2], vB2hi[0]);
    atomicAdd(&macc[16+quad*4+3][32+nlo*3+2], vB2hi[1]);
  }
  __syncthreads();

  // ---- logits: 32 edges x 8 lanes = 256 threads, one pass
  {
    const int e = t >> 3;
    const int kq = t & 7;
    const int eg = e0 + e;
    float4 ms = *(const float4*)&macc[e][kq*4];
    int dn = dst_l[e];
    const float* kvp = kvt + (size_t)dn*32 + kq*4;
    float part = ms.x*kvp[0] + ms.y*kvp[1] + ms.z*kvp[2] + ms.w*kvp[3];
    part += __shfl_xor(part, 1);
    part += __shfl_xor(part, 2);
    part += __shfl_xor(part, 4);
    if (kq == 0 && eg < E){
      float lg = (part + carr[dn]) * 0.35355339059327373f
               + logf(ntld_f(&env[eg]) + 1e-8f);
      nt_store_f(&logits_s[perm_l[e]], lg);
    }
  }

  // ---- store messages in CSR order (bf16, non-temporal)
  for (int i = t; i < 640; i += 256){
    int e = i/20, r = i - (i/20)*20;
    if (e0 + e < E){
      const float4 m4 = *(const float4*)&macc[e][r*4];
      bf16x4 b4; b4[0] = (__bf16)m4.x; b4[1] = (__bf16)m4.y;
                 b4[2] = (__bf16)m4.z; b4[3] = (__bf16)m4.w;
      nt_store_b4(msgs + (size_t)perm_l[e]*80 + r*4, b4);
    }
  }
}

// One wave per node: max pass, merged gather+den pass (bf16 msgs, NT loads),
// fused node matmuls + gate + residual + BN stats. CSR bounds from cursor
// array (cursor[n] == segment end after k_edge; start = cursor[n-1] or 0).
__global__ void __launch_bounds__(256) k_agg(
    const __bf16* __restrict__ msgs, const float* __restrict__ logits_s,
    const int* __restrict__ cursor, const float* __restrict__ nf,
    const float* __restrict__ Wout_s, const float* __restrict__ Wout_v,
    const float* __restrict__ Wg_s, const float* __restrict__ Wg_v,
    float* __restrict__ xbuf, float* __restrict__ bnacc, int N)
{
  __shared__ float aggl[4][80];
  __shared__ float t1[4][96];
  __shared__ float t2[4][96];
  __shared__ float bnl[80];
  const int t = threadIdx.x, l = t & 63, wv = t >> 6;
  const int n = blockIdx.x*4 + wv;
  const bool act = (n < N);
  const int nc = act ? n : (N-1);
  if (t < 80) bnl[t] = 0.f;

  const int r0 = (nc == 0) ? 0 : cursor[nc-1];
  const int r1 = cursor[nc];
  const int deg = act ? (r1 - r0) : 0;

  // pass 1: max logit
  float mym = -3.4e38f;
  for (int i = l; i < deg; i += 64) mym = fmaxf(mym, logits_s[r0+i]);
  #pragma unroll
  for (int s = 32; s; s >>= 1) mym = fmaxf(mym, __shfl_xor(mym, s));
  // pass 2 (merged): unnormalized gather + den
  float denp = 0.f, acc0 = 0.f, acc1 = 0.f;
  for (int c0 = 0; c0 < deg; c0 += 64){
    const int len = min(64, deg - c0);
    float ex = 0.f;
    if (l < len) ex = __expf(logits_s[r0+c0+l] - mym);
    denp += ex;
    for (int j0 = 0; j0 < len; j0 += 4){
      const int jn = len - j0;
      const __bf16* base = msgs + (size_t)(r0+c0+j0)*80;
      float v0=0,v1=0,v2=0,v3=0, w0=0,w1=0,w2=0,w3=0;
      float a0_=0,a1_=0,a2_=0,a3_=0;
      v0 = ntbf(&base[l]); if (l < 16) w0 = ntbf(&base[64+l]); a0_ = __shfl(ex, j0);
      if (jn > 1){ v1 = ntbf(&base[80+l]);  if (l < 16) w1 = ntbf(&base[144+l]); a1_ = __shfl(ex, j0+1); }
      if (jn > 2){ v2 = ntbf(&base[160+l]); if (l < 16) w2 = ntbf(&base[224+l]); a2_ = __shfl(ex, j0+2); }
      if (jn > 3){ v3 = ntbf(&base[240+l]); if (l < 16) w3 = ntbf(&base[304+l]); a3_ = __shfl(ex, j0+3); }
      acc0 += a0_*v0 + a1_*v1 + a2_*v2 + a3_*v3;
      if (l < 16) acc1 += a0_*w0 + a1_*w1 + a2_*w2 + a3_*w3;
    }
  }
  #pragma unroll
  for (int s = 32; s; s >>= 1) denp += __shfl_xor(denp, s);
  const float inv = 1.f/(denp + 1e-8f);
  aggl[wv][l] = acc0 * inv;
  if (l < 16) aggl[wv][64+l] = acc1 * inv;
  __syncthreads();

  const float* arow = &aggl[wv][0];
  const float iS = 0.17677669529663687f;  // 1/sqrt(32)
  const float iV = 0.25f;                 // 1/sqrt(16)
  for (int o = l; o < 80; o += 64){
    float val = 0.f;
    if (o < 32){
      for (int s = 0; s < 32; ++s) val += arow[s]*Wout_s[s*32+o];
      val *= iS;
    } else {
      int w = (o-32)/3, c = (o-32)-w*3;
      for (int v = 0; v < 16; ++v) val += arow[32+v*3+c]*Wout_v[v*16+w];
      val *= iV;
    }
    t1[wv][o] = val;
  }
  __syncthreads();
  for (int o = l; o < 96; o += 64){
    float val = 0.f;
    if (o < 48){
      for (int k = 0; k < 32; ++k) val += t1[wv][k]*Wg_s[k*48+o];
      val *= iS;
    } else {
      int w = (o-48)/3, c = (o-48)-w*3;
      for (int v = 0; v < 16; ++v) val += t1[wv][32+v*3+c]*Wg_v[v*16+w];
      val *= iV;
    }
    t2[wv][o] = val;
  }
  __syncthreads();
  for (int o = l; o < 80; o += 64){
    float x;
    if (o < 32){
      x = silu_f(t2[wv][o]) + nf[(size_t)nc*80+o];
      if (act){
        nt_store_f(&xbuf[(size_t)n*80+o], x);
        atomicAdd(&bnl[o], x);
        atomicAdd(&bnl[32+o], x*x);
      }
    } else {
      int w = (o-32)/3;
      x = sigm_f(t2[wv][32+w]) * t2[wv][48+(o-32)] + nf[(size_t)nc*80+o];
      if (act){
        nt_store_f(&xbuf[(size_t)n*80+o], x);
        atomicAdd(&bnl[64+w], x*x);
      }
    }
  }
  __syncthreads();
  if (t < 80) atomicAdd(&bnacc[t], bnl[t]);
}

// BN coef computed per-block (cheap), then normalize+affine
__global__ void __launch_bounds__(256) k_out(const float* __restrict__ xbuf,
    const float* __restrict__ bnacc,
    const float* __restrict__ bn_ws, const float* __restrict__ bn_bs,
    const float* __restrict__ bn_wv, float* __restrict__ out, int N){
  __shared__ float coef[80];
  int t = threadIdx.x;
  float fN = (float)N;
  if (t < 32){
    float mean = bnacc[t]/fN;
    float var = bnacc[32+t]/fN - mean*mean;
    float cm = bn_ws[t]*rsqrtf(var + 1e-5f);
    coef[t] = cm;
    coef[32+t] = bn_bs[t] - mean*cm;
  } else if (t < 48){
    int v = t - 32;
    coef[64+v] = bn_wv[v]*rsqrtf(bnacc[64+v]/(3.f*fN) + 1e-5f);
  }
  __syncthreads();
  int i = blockIdx.x*256 + t;
  if (i >= N*80) return;
  int o = i - (i/80)*80;
  float x = ntld_f(&xbuf[i]);
  nt_store_f(&out[i], (o < 32) ? (x*coef[o] + coef[32+o]) : (x*coef[64+(o-32)/3]));
}

extern "C" void kernel_launch(void* const* d_in, const int* in_sizes, int n_in,
                              void* d_out, int out_size, void* d_ws, size_t ws_size,
                              hipStream_t stream) {
  const float* nf     = (const float*)d_in[0];
  const int*   ei     = (const int*)  d_in[1];
  const float* sh     = (const float*)d_in[2];
  const float* radial = (const float*)d_in[3];
  const float* env    = (const float*)d_in[4];
  const float* W1     = (const float*)d_in[5];
  const float* b1     = (const float*)d_in[6];
  const float* W2     = (const float*)d_in[7];
  const float* b2     = (const float*)d_in[8];
  const float* Wq     = (const float*)d_in[9];
  const float* bq     = (const float*)d_in[10];
  const float* Wk     = (const float*)d_in[11];
  const float* bk     = (const float*)d_in[12];
  const float* Wout_s = (const float*)d_in[13];
  const float* Wout_v = (const float*)d_in[14];
  const float* Wg_s   = (const float*)d_in[15];
  const float* Wg_v   = (const float*)d_in[16];
  const float* bn_ws  = (const float*)d_in[17];
  const float* bn_bs  = (const float*)d_in[18];
  const float* bn_wv  = (const float*)d_in[19];

  const int E = in_sizes[4];
  const int N = in_sizes[0] / 80;

  float* ws = (float*)d_ws;
  size_t off = 0;
  __bf16* w2t    = (__bf16*)(ws + off); off += 81920;   // [2][2560][32] bf16
  __bf16* msgs   = (__bf16*)(ws + off); off += (size_t)E*40;  // E*80 bf16
  float* logits_s= ws + off; off += E;
  int* cnt       = (int*)(ws + off); off += N;
  int* cursor    = (int*)(ws + off); off += N;
  float* xbuf    = ws + off; off += (size_t)N*80;
  float* bnacc   = ws + off; off += 80;
  float* kvt     = ws + off; off += (size_t)N*32;
  float* carr    = ws + off; off += N;

  hipMemsetAsync(cnt, 0, (size_t)N*sizeof(int), stream);

  const int nbPrep = 640;                 // 163840/256
  const int nbHist = (E + 255)/256;
  const int nbKv   = (N + 63)/64;
  k_setup<<<nbPrep + nbHist + nbKv, 256, 0, stream>>>(W2, w2t, ei, cnt,
      nf, Wq, bq, Wk, bk, kvt, carr, nbPrep, nbHist, N, E);
  k_scan<<<1, 1024, 0, stream>>>(cnt, cursor, bnacc, N, E);
  k_edge<<<(E + 31)/32, 256, 0, stream>>>(nf, ei, sh, radial, env,
      W1, b1, w2t, b2, kvt, carr, cursor, msgs, logits_s, E);
  k_agg<<<(N + 3)/4, 256, 0, stream>>>(msgs, logits_s, cursor, nf,
      Wout_s, Wout_v, Wg_s, Wg_v, xbuf, bnacc, N);
  k_out<<<(N*80 + 255)/256, 256, 0, stream>>>(xbuf, bnacc, bn_ws, bn_bs, bn_wv,
      (float*)d_out, N);
}

// Round 7
// 376.210 us; speedup vs baseline: 1.2197x; 1.2197x over previous
//
#include <hip/hip_runtime.h>
#include <math.h>

typedef __bf16 bf16x8 __attribute__((ext_vector_type(8)));
typedef __bf16 bf16x4 __attribute__((ext_vector_type(4)));
typedef float  f32x4  __attribute__((ext_vector_type(4)));
typedef float  f32x2  __attribute__((ext_vector_type(2)));
typedef unsigned long long u64x2 __attribute__((ext_vector_type(2)));

__device__ __forceinline__ float silu_f(float x){ return x / (1.f + __expf(-x)); }
__device__ __forceinline__ float sigm_f(float x){ return 1.f / (1.f + __expf(-x)); }

__device__ __forceinline__ float ntld_f(const float* p){
  return __builtin_nontemporal_load(p);
}
__device__ __forceinline__ float ntbf(const __bf16* p){
  unsigned short us = __builtin_nontemporal_load((const unsigned short*)p);
  union { unsigned u; float f; } cv; cv.u = ((unsigned)us) << 16;
  return cv.f;
}
__device__ __forceinline__ void nt_store_f(float* p, float v){
  __builtin_nontemporal_store(v, p);
}
__device__ __forceinline__ void nt_store_b8(__bf16* p, bf16x8 v){
  u64x2 u; __builtin_memcpy(&u, &v, 16);
  __builtin_nontemporal_store(u, (u64x2*)p);
}
__device__ __forceinline__ f32x2 b4lo(bf16x4 v){ f32x2 r; r[0]=(float)v[0]; r[1]=(float)v[1]; return r; }
__device__ __forceinline__ f32x2 b4hi(bf16x4 v){ f32x2 r; r[0]=(float)v[2]; r[1]=(float)v[3]; return r; }

// Block ranges: [0,nbPrep) W2->bf16 transpose; [nbPrep,+nbHist) dst histogram;
// rest: per-node attention vectors kv[n]=Wk@(nf@Wq+bq), c[n]=(nf@Wq+bq).bk
__global__ void __launch_bounds__(256) k_setup(const float* __restrict__ W2,
    __bf16* __restrict__ W2t, const int* __restrict__ ei, int* __restrict__ cnt,
    const float* __restrict__ nf, const float* __restrict__ Wq,
    const float* __restrict__ bq, const float* __restrict__ Wk,
    const float* __restrict__ bk, float* __restrict__ kvt, float* __restrict__ carr,
    int nbPrep, int nbHist, int N, int E){
  int b = blockIdx.x, t = threadIdx.x;
  if (b < nbPrep){
    int gid = b*256 + t;   // 163840 total
    int h = gid / 2560;
    int col = gid - h*2560;
    W2t[(size_t)(h>>5)*81920 + col*32 + (h&31)] = (__bf16)ntld_f(&W2[gid]);
    return;
  }
  if (b < nbPrep + nbHist){
    int e = (b - nbPrep)*256 + t;
    if (e < E) atomicAdd(&cnt[ei[E+e]], 1);
    return;
  }
  __shared__ float M[32][33];
  __shared__ float mb[32];
  __shared__ float nfl[64][33];
  __shared__ float bqbk_s;
  const int n0 = (b - nbPrep - nbHist)*64;
  for (int idx = t; idx < 1024; idx += 256){
    int s = idx >> 5, i = idx & 31;
    float acc = 0.f;
    #pragma unroll
    for (int j = 0; j < 8; ++j) acc += Wq[s*8+j]*Wk[i*8+j];
    M[s][i] = acc;
  }
  if (t < 32){
    float acc = 0.f;
    #pragma unroll
    for (int j = 0; j < 8; ++j) acc += Wq[t*8+j]*bk[j];
    mb[t] = acc;
  }
  if (t == 0){
    float acc = 0.f;
    #pragma unroll
    for (int j = 0; j < 8; ++j) acc += bq[j]*bk[j];
    bqbk_s = acc;
  }
  for (int idx = t; idx < 2048; idx += 256){
    int nl = idx >> 5, s = idx & 31;
    int n = n0 + nl;
    nfl[nl][s] = (n < N) ? nf[(size_t)n*80 + s] : 0.f;
  }
  __syncthreads();
  for (int idx = t; idx < 2048; idx += 256){
    int nl = idx >> 5, i = idx & 31;
    int n = n0 + nl;
    if (n < N){
      float acc = 0.f;
      #pragma unroll 8
      for (int s = 0; s < 32; ++s) acc += nfl[nl][s]*M[s][i];
      kvt[(size_t)n*32 + i] = acc;
    }
  }
  if (t < 64){
    int n = n0 + t;
    if (n < N){
      float acc = bqbk_s;
      #pragma unroll 8
      for (int s = 0; s < 32; ++s) acc += nfl[t][s]*mb[s];
      carr[n] = acc;
    }
  }
}

__global__ void __launch_bounds__(1024) k_scan(const int* __restrict__ cnt,
    int* __restrict__ cursor, float* __restrict__ bnacc, int N, int E){
  __shared__ int part[1024];
  int t = threadIdx.x;
  if (t < 80) bnacc[t] = 0.f;
  int chunk = (N + 1023) >> 10;
  int lo = t*chunk, hi = min(lo+chunk, N);
  int s = 0;
  for (int i = lo; i < hi; ++i) s += cnt[i];
  part[t] = s;
  __syncthreads();
  for (int off = 1; off < 1024; off <<= 1){
    int v = (t >= off) ? part[t-off] : 0;
    __syncthreads();
    part[t] += v;
    __syncthreads();
  }
  int base = (t == 0) ? 0 : part[t-1];
  for (int i = lo; i < hi; ++i){
    cursor[i] = base;
    base += cnt[i];
  }
}

// Per-edge precompute: u = silu(radial@W1+b1) (bf16, MFMA-A tiled layout),
// coefficient tables cAB/cV (bf16, tile-transposed), CSR perm. 64 edges/block.
__global__ void __launch_bounds__(256) k_prep(
    const float* __restrict__ nf, const int* __restrict__ ei,
    const float* __restrict__ sh, const float* __restrict__ radial,
    const float* __restrict__ W1, const float* __restrict__ b1,
    int* __restrict__ cursor,
    __bf16* __restrict__ uG, __bf16* __restrict__ cabG, __bf16* __restrict__ cvG,
    int* __restrict__ permG, int E, int NT)
{
  __shared__ float featT[80][65];
  __shared__ float radl[64][17];
  __shared__ float shlT[4][64];
  __shared__ float w1l[1024];
  __shared__ float b1l[64];
  __shared__ __align__(16) __bf16 u_l[64][72];
  __shared__ __align__(16) __bf16 cab_l[48][64];
  __shared__ __align__(16) __bf16 cv_l[64][3][64];
  __shared__ int src_l[64];

  const int t = threadIdx.x;
  const int e0 = blockIdx.x*64;
  const int tg0 = blockIdx.x*4;

  if (t < 64){
    int ee = e0 + t;
    if (ee < E){
      src_l[t] = ei[ee];
      permG[ee] = atomicAdd(&cursor[ei[(size_t)E+ee]], 1);
    } else src_l[t] = ei[E-1];
    b1l[t] = b1[t];
  }
  {
    int e = t >> 2, c = t & 3;
    int ec = min(e0+e, E-1);
    shlT[c][e] = ntld_f(&sh[(size_t)ec*4+c]);
  }
  for (int i = t; i < 1024; i += 256){
    int e = i >> 4, r = i & 15;
    int ec = min(e0+e, E-1);
    radl[e][r] = ntld_f(&radial[(size_t)ec*16+r]);
  }
  *(float4*)&w1l[t*4] = ((const float4*)W1)[t];
  __syncthreads();

  for (int i = t; i < 5120; i += 256){
    int e = i / 80, idx = i - e*80;
    featT[idx][e] = nf[(size_t)src_l[e]*80 + idx];
  }
  for (int i = t; i < 4096; i += 256){
    int e = i & 63, h = i >> 6;
    float acc = b1l[h];
    #pragma unroll
    for (int r = 0; r < 16; ++r) acc += radl[e][r]*w1l[r*64+h];
    u_l[e][h] = (__bf16)silu_f(acc);
  }
  __syncthreads();

  const float inv_s3 = 0.57735026918962576f;
  const float inv_s2 = 0.70710678118654752f;
  const float a0 = 0.14433756729740643f;  // 1/sqrt(48)
  const float a1 = 0.125f;                // 1/sqrt(64)

  for (int i = t; i < 3072; i += 256){
    int r = i >> 6, e = i & 63;
    float val;
    if (r < 32) val = a0 * shlT[0][e] * featT[r][e];
    else {
      int v = r - 32;
      float dot = (featT[32+v*3][e]*shlT[1][e] + featT[33+v*3][e]*shlT[2][e]
                 + featT[34+v*3][e]*shlT[3][e]) * inv_s3;
      val = a0 * dot;
    }
    cab_l[r][e] = (__bf16)val;
  }
  for (int i = t; i < 12288; i += 256){
    int e = i & 63, r = (i >> 6) & 63, c = i >> 12;
    float val;
    if (r < 32) val = a1 * shlT[1+c][e] * featT[r][e];
    else if (r < 48){
      int v = r - 32;
      val = a1 * shlT[0][e] * featT[32+v*3+c][e];
    } else {
      int v = r - 48;
      int c1 = c+1; if (c1 > 2) c1 -= 3;
      int c2 = c+2; if (c2 > 2) c2 -= 3;
      val = a1 * inv_s2 * (featT[32+v*3+c1][e]*shlT[1+c2][e]
                         - featT[32+v*3+c2][e]*shlT[1+c1][e]);
    }
    cv_l[r][c][e] = (__bf16)val;
  }
  __syncthreads();

  // ---- tiled outputs (16 edges per tile; tile layouts match k_edge lanes)
  // uG[tile]: [k8][e][j8] bf16 (2048 B)
  for (int i = t; i < 512; i += 256){
    int tl = i >> 7, rem = i & 127, k8 = rem >> 4, e = rem & 15;
    if (tg0 + tl < NT){
      bf16x8 v = *(const bf16x8*)&u_l[tl*16 + e][k8*8];
      *(bf16x8*)((char*)uG + (size_t)(tg0+tl)*2048 + k8*256 + e*16) = v;
    }
  }
  // cabG[tile]: [r48][e16] bf16 (1536 B)
  for (int i = t; i < 384; i += 256){
    int tl = i / 96, rem = i - tl*96, r = rem >> 1, h = rem & 1;
    if (tg0 + tl < NT){
      bf16x8 v = *(const bf16x8*)&cab_l[r][tl*16 + h*8];
      *(bf16x8*)((char*)cabG + (size_t)(tg0+tl)*1536 + r*32 + h*16) = v;
    }
  }
  // cvG[tile]: [r64][c3][e16] bf16 (6144 B)
  for (int i = t; i < 1536; i += 256){
    int tl = i / 384, rem = i - tl*384, r = rem / 6, rem2 = rem - r*6,
        c = rem2 >> 1, h = rem2 & 1;
    if (tg0 + tl < NT){
      bf16x8 v = *(const bf16x8*)&cv_l[r][c][tl*16 + h*8];
      *(bf16x8*)((char*)cvG + (size_t)(tg0+tl)*6144 + r*96 + c*32 + h*16) = v;
    }
  }
}

#define LOAD_PANEL(BASE_IT, NITS) do {                                         \
    for (int idx = t; idx < (NITS)*128; idx += 512){                           \
      int itl_ = idx >> 7, rem_ = idx & 127, half_ = rem_ >> 6, o16_ = rem_ & 63;\
      *(float4*)(panel + itl_*2048 + half_*1024 + o16_*16) =                   \
        *(const float4*)(w2b + half_*163840 + (size_t)((BASE_IT)+itl_)*1024 + o16_*16);\
    }                                                                          \
    for (int i = t; i < (NITS)*16; i += 512) b2l[i] = b2[(BASE_IT)*16 + i];    \
  } while(0)

#define S_PHASE(SECOND) do {                                                   \
  int tg = wgid;                                                               \
  if (tg < NT){                                                                \
    bf16x8 uA  = *(const bf16x8*)(uGb + (size_t)tg*2048 + uOff);               \
    bf16x8 uBq = *(const bf16x8*)(uGb + (size_t)tg*2048 + 1024 + uOff);        \
    bf16x8 cb16 = *(const bf16x8*)(cabGb + (size_t)tg*1536 + lane*16);         \
    bf16x4 cb8  = *(const bf16x4*)(cabGb + (size_t)tg*1536 + 1024 + lane*8);   \
    f32x4 p0; p0[0]=0;p0[1]=0;p0[2]=0;p0[3]=0; f32x4 p1 = p0;                  \
    if (SECOND){                                                               \
      p0 = *(const f32x4*)(partU + (size_t)tg*768 + lane*8);                   \
      p1 = *(const f32x4*)(partU + (size_t)tg*768 + lane*8 + 4);               \
    }                                                                          \
    for (;;){                                                                  \
      const int tgn = tg + 2048;                                               \
      const bool hn = (tgn < NT);                                              \
      *(bf16x8*)(myCab + lane*16) = cb16;                                      \
      *(bf16x4*)(myCab + 1024 + lane*8) = cb8;                                 \
      const bf16x8 afr0 = uA, afr1 = uBq;                                      \
      bf16x8 uA_n = uA, uB_n = uBq, cb16_n = cb16; bf16x4 cb8_n = cb8;         \
      f32x4 p0_n = p0, p1_n = p1;                                              \
      if (hn){                                                                 \
        uA_n  = *(const bf16x8*)(uGb + (size_t)tgn*2048 + uOff);               \
        uB_n  = *(const bf16x8*)(uGb + (size_t)tgn*2048 + 1024 + uOff);        \
        cb16_n = *(const bf16x8*)(cabGb + (size_t)tgn*1536 + lane*16);         \
        cb8_n  = *(const bf16x4*)(cabGb + (size_t)tgn*1536 + 1024 + lane*8);   \
        if (SECOND){                                                           \
          p0_n = *(const f32x4*)(partU + (size_t)tgn*768 + lane*8);            \
          p1_n = *(const f32x4*)(partU + (size_t)tgn*768 + lane*8 + 4);        \
        }                                                                      \
      }                                                                        \
      f32x2 s0lo, s0hi, s1lo, s1hi;                                            \
      s0lo[0]=p0[0]; s0lo[1]=p0[1]; s0hi[0]=p0[2]; s0hi[1]=p0[3];              \
      s1lo[0]=p1[0]; s1lo[1]=p1[1]; s1hi[0]=p1[2]; s1hi[1]=p1[3];              \
      _Pragma("unroll 4")                                                      \
      for (int itl = 0; itl < 48; ++itl){                                      \
        bf16x8 B0 = *(const bf16x8*)(panel + itl*2048 + laneOff);              \
        bf16x8 B1 = *(const bf16x8*)(panel + itl*2048 + 1024 + laneOff);       \
        f32x4 d; d[0]=0;d[1]=0;d[2]=0;d[3]=0;                                  \
        d = __builtin_amdgcn_mfma_f32_16x16x32_bf16(afr0, B0, d, 0,0,0);       \
        d = __builtin_amdgcn_mfma_f32_16x16x32_bf16(afr1, B1, d, 0,0,0);       \
        const float bias = b2l[itl*16 + nlo];                                  \
        f32x2 bb; bb[0]=bias; bb[1]=bias;                                      \
        f32x2 dlo = __builtin_shufflevector(d,d,0,1) + bb;                     \
        f32x2 dhi = __builtin_shufflevector(d,d,2,3) + bb;                     \
        const int r = (SECOND)*24 + (itl>>1);                                  \
        bf16x4 c4 = *(const bf16x4*)(myCab + r*32 + quad*8);                   \
        if (itl & 1){ s1lo += b4lo(c4)*dlo; s1hi += b4hi(c4)*dhi; }            \
        else        { s0lo += b4lo(c4)*dlo; s0hi += b4hi(c4)*dhi; }            \
      }                                                                        \
      if (!(SECOND)){                                                          \
        f32x4 P0; P0[0]=s0lo[0]; P0[1]=s0lo[1]; P0[2]=s0hi[0]; P0[3]=s0hi[1];  \
        f32x4 P1; P1[0]=s1lo[0]; P1[1]=s1lo[1]; P1[2]=s1hi[0]; P1[3]=s1hi[1];  \
        *(f32x4*)(partU + (size_t)tg*768 + lane*8) = P0;                       \
        *(f32x4*)(partU + (size_t)tg*768 + lane*8 + 4) = P1;                   \
      } else {                                                                 \
        const int eb = quad*4;                                                 \
        myOut[(eb+0)*56 + nlo] = s0lo[0];                                      \
        myOut[(eb+1)*56 + nlo] = s0lo[1];                                      \
        myOut[(eb+2)*56 + nlo] = s0hi[0];                                      \
        myOut[(eb+3)*56 + nlo] = s0hi[1];                                      \
        myOut[(eb+0)*56 + 16+nlo] = s1lo[0];                                   \
        myOut[(eb+1)*56 + 16+nlo] = s1lo[1];                                   \
        myOut[(eb+2)*56 + 16+nlo] = s1hi[0];                                   \
        myOut[(eb+3)*56 + 16+nlo] = s1hi[1];                                   \
        const int e0e = tg*16;                                                 \
        { int e = lane>>2, seg = lane&3, eg = e0e + e;                         \
          if (eg < E){                                                         \
            f32x4 m0 = *(const f32x4*)&myOut[e*56 + seg*8];                    \
            f32x4 m1 = *(const f32x4*)&myOut[e*56 + seg*8 + 4];                \
            bf16x8 o; o[0]=(__bf16)m0[0]; o[1]=(__bf16)m0[1];                  \
            o[2]=(__bf16)m0[2]; o[3]=(__bf16)m0[3]; o[4]=(__bf16)m1[0];        \
            o[5]=(__bf16)m1[1]; o[6]=(__bf16)m1[2]; o[7]=(__bf16)m1[3];        \
            nt_store_b8(msgs + (size_t)permG[eg]*80 + seg*8, o);               \
          } }                                                                  \
        for (int r8 = 0; r8 < 2; ++r8){                                        \
          int e = r8*8 + (lane>>3), kq = lane&7, eg = e0e + e;                 \
          f32x4 ms = *(const f32x4*)&myOut[e*56 + kq*4];                       \
          int dn = ei[(size_t)E + min(eg, E-1)];                               \
          const float* kvp = kvt + (size_t)dn*32 + kq*4;                       \
          float part = ms[0]*kvp[0]+ms[1]*kvp[1]+ms[2]*kvp[2]+ms[3]*kvp[3];    \
          part += __shfl_xor(part, 1);                                         \
          part += __shfl_xor(part, 2);                                         \
          part += __shfl_xor(part, 4);                                         \
          if (kq == 0 && eg < E){                                              \
            float lg = (part + carr[dn]) * 0.35355339059327373f                \
                     + logf(ntld_f(&env[eg]) + 1e-8f);                         \
            nt_store_f(&logits_s[permG[eg]], lg);                              \
          } }                                                                  \
      }                                                                        \
      if (!hn) break;                                                          \
      uA = uA_n; uBq = uB_n; cb16 = cb16_n; cb8 = cb8_n;                       \
      p0 = p0_n; p1 = p1_n;                                                    \
      tg = tgn;                                                                \
    }                                                                          \
  }                                                                            \
} while(0)

#define V_PHASE(SECOND) do {                                                   \
  int tg = wgid;                                                               \
  if (tg < NT){                                                                \
    bf16x8 uA  = *(const bf16x8*)(uGb + (size_t)tg*2048 + uOff);               \
    bf16x8 uBq = *(const bf16x8*)(uGb + (size_t)tg*2048 + 1024 + uOff);        \
    bf16x8 cv0 = *(const bf16x8*)(cvGb + (size_t)tg*6144 + (SECOND)*3072 + lane*48);\
    bf16x8 cv1 = *(const bf16x8*)(cvGb + (size_t)tg*6144 + (SECOND)*3072 + lane*48 + 16);\
    bf16x8 cv2 = *(const bf16x8*)(cvGb + (size_t)tg*6144 + (SECOND)*3072 + lane*48 + 32);\
    f32x4 p0; p0[0]=0;p0[1]=0;p0[2]=0;p0[3]=0; f32x4 p1 = p0, p2 = p0;         \
    if (SECOND){                                                               \
      p0 = *(const f32x4*)(partU + (size_t)tg*768 + lane*12);                  \
      p1 = *(const f32x4*)(partU + (size_t)tg*768 + lane*12 + 4);              \
      p2 = *(const f32x4*)(partU + (size_t)tg*768 + lane*12 + 8);              \
    }                                                                          \
    for (;;){                                                                  \
      const int tgn = tg + 2048;                                               \
      const bool hn = (tgn < NT);                                              \
      *(bf16x8*)(myCab + lane*48)      = cv0;                                  \
      *(bf16x8*)(myCab + lane*48 + 16) = cv1;                                  \
      *(bf16x8*)(myCab + lane*48 + 32) = cv2;                                  \
      const bf16x8 afr0 = uA, afr1 = uBq;                                      \
      bf16x8 uA_n = uA, uB_n = uBq, cv0_n = cv0, cv1_n = cv1, cv2_n = cv2;     \
      f32x4 p0_n = p0, p1_n = p1, p2_n = p2;                                   \
      if (hn){                                                                 \
        uA_n = *(const bf16x8*)(uGb + (size_t)tgn*2048 + uOff);                \
        uB_n = *(const bf16x8*)(uGb + (size_t)tgn*2048 + 1024 + uOff);         \
        cv0_n = *(const bf16x8*)(cvGb + (size_t)tgn*6144 + (SECOND)*3072 + lane*48);\
        cv1_n = *(const bf16x8*)(cvGb + (size_t)tgn*6144 + (SECOND)*3072 + lane*48 + 16);\
        cv2_n = *(const bf16x8*)(cvGb + (size_t)tgn*6144 + (SECOND)*3072 + lane*48 + 32);\
        if (SECOND){                                                           \
          p0_n = *(const f32x4*)(partU + (size_t)tgn*768 + lane*12);           \
          p1_n = *(const f32x4*)(partU + (size_t)tgn*768 + lane*12 + 4);       \
          p2_n = *(const f32x4*)(partU + (size_t)tgn*768 + lane*12 + 8);       \
        }                                                                      \
      }                                                                        \
      f32x2 v0lo, v0hi, v1lo, v1hi, v2lo, v2hi;                                \
      v0lo[0]=p0[0]; v0lo[1]=p0[1]; v0hi[0]=p0[2]; v0hi[1]=p0[3];              \
      v1lo[0]=p1[0]; v1lo[1]=p1[1]; v1hi[0]=p1[2]; v1hi[1]=p1[3];              \
      v2lo[0]=p2[0]; v2lo[1]=p2[1]; v2hi[0]=p2[2]; v2hi[1]=p2[3];              \
      _Pragma("unroll 4")                                                      \
      for (int itl = 0; itl < 32; ++itl){                                      \
        bf16x8 B0 = *(const bf16x8*)(panel + itl*2048 + laneOff);              \
        bf16x8 B1 = *(const bf16x8*)(panel + itl*2048 + 1024 + laneOff);       \
        f32x4 d; d[0]=0;d[1]=0;d[2]=0;d[3]=0;                                  \
        d = __builtin_amdgcn_mfma_f32_16x16x32_bf16(afr0, B0, d, 0,0,0);       \
        d = __builtin_amdgcn_mfma_f32_16x16x32_bf16(afr1, B1, d, 0,0,0);       \
        const float bias = b2l[itl*16 + nlo];                                  \
        f32x2 bb; bb[0]=bias; bb[1]=bias;                                      \
        f32x2 dlo = __builtin_shufflevector(d,d,0,1) + bb;                     \
        f32x2 dhi = __builtin_shufflevector(d,d,2,3) + bb;                     \
        const char* cb_ = myCab + itl*96;                                      \
        bf16x4 q0 = *(const bf16x4*)(cb_ + quad*8);                            \
        bf16x4 q1 = *(const bf16x4*)(cb_ + 32 + quad*8);                       \
        bf16x4 q2 = *(const bf16x4*)(cb_ + 64 + quad*8);                       \
        v0lo += b4lo(q0)*dlo; v0hi += b4hi(q0)*dhi;                            \
        v1lo += b4lo(q1)*dlo; v1hi += b4hi(q1)*dhi;                            \
        v2lo += b4lo(q2)*dlo; v2hi += b4hi(q2)*dhi;                            \
      }                                                                        \
      if (!(SECOND)){                                                          \
        f32x4 P0; P0[0]=v0lo[0]; P0[1]=v0lo[1]; P0[2]=v0hi[0]; P0[3]=v0hi[1];  \
        f32x4 P1; P1[0]=v1lo[0]; P1[1]=v1lo[1]; P1[2]=v1hi[0]; P1[3]=v1hi[1];  \
        f32x4 P2; P2[0]=v2lo[0]; P2[1]=v2lo[1]; P2[2]=v2hi[0]; P2[3]=v2hi[1];  \
        *(f32x4*)(partU + (size_t)tg*768 + lane*12)     = P0;                  \
        *(f32x4*)(partU + (size_t)tg*768 + lane*12 + 4) = P1;                  \
        *(f32x4*)(partU + (size_t)tg*768 + lane*12 + 8) = P2;                  \
      } else {                                                                 \
        const int eb = quad*4; const int cb2 = nlo*3;                          \
        myOut[(eb+0)*56 + cb2+0] = v0lo[0];                                    \
        myOut[(eb+1)*56 + cb2+0] = v0lo[1];                                    \
        myOut[(eb+2)*56 + cb2+0] = v0hi[0];                                    \
        myOut[(eb+3)*56 + cb2+0] = v0hi[1];                                    \
        myOut[(eb+0)*56 + cb2+1] = v1lo[0];                                    \
        myOut[(eb+1)*56 + cb2+1] = v1lo[1];                                    \
        myOut[(eb+2)*56 + cb2+1] = v1hi[0];                                    \
        myOut[(eb+3)*56 + cb2+1] = v1hi[1];                                    \
        myOut[(eb+0)*56 + cb2+2] = v2lo[0];                                    \
        myOut[(eb+1)*56 + cb2+2] = v2lo[1];                                    \
        myOut[(eb+2)*56 + cb2+2] = v2hi[0];                                    \
        myOut[(eb+3)*56 + cb2+2] = v2hi[1];                                    \
        const int e0e = tg*16;                                                 \
        for (int i = lane; i < 96; i += 64){                                   \
          int e = i/6, seg = i - (i/6)*6, eg = e0e + e;                        \
          if (eg < E){                                                         \
            f32x4 m0 = *(const f32x4*)&myOut[e*56 + seg*8];                    \
            f32x4 m1 = *(const f32x4*)&myOut[e*56 + seg*8 + 4];                \
            bf16x8 o; o[0]=(__bf16)m0[0]; o[1]=(__bf16)m0[1];                  \
            o[2]=(__bf16)m0[2]; o[3]=(__bf16)m0[3]; o[4]=(__bf16)m1[0];        \
            o[5]=(__bf16)m1[1]; o[6]=(__bf16)m1[2]; o[7]=(__bf16)m1[3];        \
            nt_store_b8(msgs + (size_t)permG[eg]*80 + 32 + seg*8, o);          \
          } }                                                                  \
      }                                                                        \
      if (!hn) break;                                                          \
      uA = uA_n; uBq = uB_n; cv0 = cv0_n; cv1 = cv1_n; cv2 = cv2_n;            \
      p0 = p0_n; p1 = p1_n; p2 = p2_n;                                         \
      tg = tgn;                                                                \
    }                                                                          \
  }                                                                            \
} while(0)

// Persistent-panel edge kernel: 256 blocks x 512 threads (1 block/CU).
// 4 phases, each loads a W2t panel (<=96 KB) into LDS once; waves stream
// their private 16-edge tiles against it with pure ds_read feeds (no global
// loads in inner loop). Cross-phase partials are wave-private f32 in global
// (XCD-L2 resident). W2t total traffic: 2 GB -> ~98 MB.
__global__ void __launch_bounds__(512, 1) k_edge(
    const __bf16* __restrict__ W2t, const float* __restrict__ b2,
    const __bf16* __restrict__ uG, const __bf16* __restrict__ cabG,
    const __bf16* __restrict__ cvG, const int* __restrict__ ei,
    const int* __restrict__ permG, const float* __restrict__ kvt,
    const float* __restrict__ carr, const float* __restrict__ env,
    float* __restrict__ partU, __bf16* __restrict__ msgs,
    float* __restrict__ logits_s, int E, int NT)
{
  __shared__ __align__(16) char panel[98304];      // 48 its x 2048 B
  __shared__ __align__(16) char wstage[8][6656];   // per wave: cab/cv 3072 + out f32[16][56]
  __shared__ float b2l[768];

  const int t = threadIdx.x;
  const int lane = t & 63;
  const int wv   = t >> 6;
  const int quad = lane >> 4;
  const int nlo  = lane & 15;
  const int wgid = blockIdx.x*8 + wv;
  const int laneOff = nlo*64 + quad*16;   // panel B-fragment byte offset
  const int uOff    = quad*256 + nlo*16;  // u A-fragment byte offset
  char*  myCab = wstage[wv];
  float* myOut = (float*)(wstage[wv] + 3072);
  const char* w2b   = (const char*)W2t;
  const char* uGb   = (const char*)uG;
  const char* cabGb = (const char*)cabG;
  const char* cvGb  = (const char*)cvG;

  LOAD_PANEL(0, 48);
  __syncthreads();
  S_PHASE(0);
  __syncthreads();
  LOAD_PANEL(48, 48);
  __syncthreads();
  S_PHASE(1);
  __syncthreads();
  LOAD_PANEL(96, 32);
  __syncthreads();
  V_PHASE(0);
  __syncthreads();
  LOAD_PANEL(128, 32);
  __syncthreads();
  V_PHASE(1);
}

// One wave per node: max pass, merged gather+den pass (bf16 msgs, NT loads),
// fused node matmuls + gate + residual + BN stats.
__global__ void __launch_bounds__(256) k_agg(
    const __bf16* __restrict__ msgs, const float* __restrict__ logits_s,
    const int* __restrict__ cursor, const float* __restrict__ nf,
    const float* __restrict__ Wout_s, const float* __restrict__ Wout_v,
    const float* __restrict__ Wg_s, const float* __restrict__ Wg_v,
    float* __restrict__ xbuf, float* __restrict__ bnacc, int N)
{
  __shared__ float aggl[4][80];
  __shared__ float t1[4][96];
  __shared__ float t2[4][96];
  __shared__ float bnl[80];
  const int t = threadIdx.x, l = t & 63, wv = t >> 6;
  const int n = blockIdx.x*4 + wv;
  const bool act = (n < N);
  const int nc = act ? n : (N-1);
  if (t < 80) bnl[t] = 0.f;

  const int r0 = (nc == 0) ? 0 : cursor[nc-1];
  const int r1 = cursor[nc];
  const int deg = act ? (r1 - r0) : 0;

  float mym = -3.4e38f;
  for (int i = l; i < deg; i += 64) mym = fmaxf(mym, logits_s[r0+i]);
  #pragma unroll
  for (int s = 32; s; s >>= 1) mym = fmaxf(mym, __shfl_xor(mym, s));
  float denp = 0.f, acc0 = 0.f, acc1 = 0.f;
  for (int c0 = 0; c0 < deg; c0 += 64){
    const int len = min(64, deg - c0);
    float ex = 0.f;
    if (l < len) ex = __expf(logits_s[r0+c0+l] - mym);
    denp += ex;
    for (int j0 = 0; j0 < len; j0 += 4){
      const int jn = len - j0;
      const __bf16* base = msgs + (size_t)(r0+c0+j0)*80;
      float v0=0,v1=0,v2=0,v3=0, w0=0,w1=0,w2=0,w3=0;
      float a0_=0,a1_=0,a2_=0,a3_=0;
      v0 = ntbf(&base[l]); if (l < 16) w0 = ntbf(&base[64+l]); a0_ = __shfl(ex, j0);
      if (jn > 1){ v1 = ntbf(&base[80+l]);  if (l < 16) w1 = ntbf(&base[144+l]); a1_ = __shfl(ex, j0+1); }
      if (jn > 2){ v2 = ntbf(&base[160+l]); if (l < 16) w2 = ntbf(&base[224+l]); a2_ = __shfl(ex, j0+2); }
      if (jn > 3){ v3 = ntbf(&base[240+l]); if (l < 16) w3 = ntbf(&base[304+l]); a3_ = __shfl(ex, j0+3); }
      acc0 += a0_*v0 + a1_*v1 + a2_*v2 + a3_*v3;
      if (l < 16) acc1 += a0_*w0 + a1_*w1 + a2_*w2 + a3_*w3;
    }
  }
  #pragma unroll
  for (int s = 32; s; s >>= 1) denp += __shfl_xor(denp, s);
  const float inv = 1.f/(denp + 1e-8f);
  aggl[wv][l] = acc0 * inv;
  if (l < 16) aggl[wv][64+l] = acc1 * inv;
  __syncthreads();

  const float* arow = &aggl[wv][0];
  const float iS = 0.17677669529663687f;  // 1/sqrt(32)
  const float iV = 0.25f;                 // 1/sqrt(16)
  for (int o = l; o < 80; o += 64){
    float val = 0.f;
    if (o < 32){
      for (int s = 0; s < 32; ++s) val += arow[s]*Wout_s[s*32+o];
      val *= iS;
    } else {
      int w = (o-32)/3, c = (o-32)-w*3;
      for (int v = 0; v < 16; ++v) val += arow[32+v*3+c]*Wout_v[v*16+w];
      val *= iV;
    }
    t1[wv][o] = val;
  }
  __syncthreads();
  for (int o = l; o < 96; o += 64){
    float val = 0.f;
    if (o < 48){
      for (int k = 0; k < 32; ++k) val += t1[wv][k]*Wg_s[k*48+o];
      val *= iS;
    } else {
      int w = (o-48)/3, c = (o-48)-w*3;
      for (int v = 0; v < 16; ++v) val += t1[wv][32+v*3+c]*Wg_v[v*16+w];
      val *= iV;
    }
    t2[wv][o] = val;
  }
  __syncthreads();
  for (int o = l; o < 80; o += 64){
    float x;
    if (o < 32){
      x = silu_f(t2[wv][o]) + nf[(size_t)nc*80+o];
      if (act){
        nt_store_f(&xbuf[(size_t)n*80+o], x);
        atomicAdd(&bnl[o], x);
        atomicAdd(&bnl[32+o], x*x);
      }
    } else {
      int w = (o-32)/3;
      x = sigm_f(t2[wv][32+w]) * t2[wv][48+(o-32)] + nf[(size_t)nc*80+o];
      if (act){
        nt_store_f(&xbuf[(size_t)n*80+o], x);
        atomicAdd(&bnl[64+w], x*x);
      }
    }
  }
  __syncthreads();
  if (t < 80) atomicAdd(&bnacc[t], bnl[t]);
}

__global__ void __launch_bounds__(256) k_out(const float* __restrict__ xbuf,
    const float* __restrict__ bnacc,
    const float* __restrict__ bn_ws, const float* __restrict__ bn_bs,
    const float* __restrict__ bn_wv, float* __restrict__ out, int N){
  __shared__ float coef[80];
  int t = threadIdx.x;
  float fN = (float)N;
  if (t < 32){
    float mean = bnacc[t]/fN;
    float var = bnacc[32+t]/fN - mean*mean;
    float cm = bn_ws[t]*rsqrtf(var + 1e-5f);
    coef[t] = cm;
    coef[32+t] = bn_bs[t] - mean*cm;
  } else if (t < 48){
    int v = t - 32;
    coef[64+v] = bn_wv[v]*rsqrtf(bnacc[64+v]/(3.f*fN) + 1e-5f);
  }
  __syncthreads();
  int i = blockIdx.x*256 + t;
  if (i >= N*80) return;
  int o = i - (i/80)*80;
  float x = ntld_f(&xbuf[i]);
  nt_store_f(&out[i], (o < 32) ? (x*coef[o] + coef[32+o]) : (x*coef[64+(o-32)/3]));
}

extern "C" void kernel_launch(void* const* d_in, const int* in_sizes, int n_in,
                              void* d_out, int out_size, void* d_ws, size_t ws_size,
                              hipStream_t stream) {
  const float* nf     = (const float*)d_in[0];
  const int*   ei     = (const int*)  d_in[1];
  const float* sh     = (const float*)d_in[2];
  const float* radial = (const float*)d_in[3];
  const float* env    = (const float*)d_in[4];
  const float* W1     = (const float*)d_in[5];
  const float* b1     = (const float*)d_in[6];
  const float* W2     = (const float*)d_in[7];
  const float* b2     = (const float*)d_in[8];
  const float* Wq     = (const float*)d_in[9];
  const float* bq     = (const float*)d_in[10];
  const float* Wk     = (const float*)d_in[11];
  const float* bk     = (const float*)d_in[12];
  const float* Wout_s = (const float*)d_in[13];
  const float* Wout_v = (const float*)d_in[14];
  const float* Wg_s   = (const float*)d_in[15];
  const float* Wg_v   = (const float*)d_in[16];
  const float* bn_ws  = (const float*)d_in[17];
  const float* bn_bs  = (const float*)d_in[18];
  const float* bn_wv  = (const float*)d_in[19];

  const int E = in_sizes[4];
  const int N = in_sizes[0] / 80;
  const int NT = (E + 15)/16;

  float* ws = (float*)d_ws;
  size_t off = 0;
  __bf16* w2t    = (__bf16*)(ws + off); off += 81920;          // 320 KB bf16
  __bf16* msgs   = (__bf16*)(ws + off); off += (size_t)E*40;   // E*80 bf16
  float* logits_s= ws + off; off += E;
  int* cnt       = (int*)(ws + off); off += N;
  int* cursor    = (int*)(ws + off); off += N;
  float* xbuf    = ws + off; off += (size_t)N*80;
  float* bnacc   = ws + off; off += 80;
  float* kvt     = ws + off; off += (size_t)N*32;
  float* carr    = ws + off; off += N;
  int* permG     = (int*)(ws + off); off += E;
  __bf16* uG     = (__bf16*)(ws + off); off += (size_t)NT*512;   // NT*2048 B
  __bf16* cabG   = (__bf16*)(ws + off); off += (size_t)NT*384;   // NT*1536 B
  __bf16* cvG    = (__bf16*)(ws + off); off += (size_t)NT*1536;  // NT*6144 B
  float* partU   = ws + off; off += (size_t)NT*768;              // NT*3072 B

  hipMemsetAsync(cnt, 0, (size_t)N*sizeof(int), stream);

  const int nbPrep = 640;                 // 163840/256
  const int nbHist = (E + 255)/256;
  const int nbKv   = (N + 63)/64;
  k_setup<<<nbPrep + nbHist + nbKv, 256, 0, stream>>>(W2, w2t, ei, cnt,
      nf, Wq, bq, Wk, bk, kvt, carr, nbPrep, nbHist, N, E);
  k_scan<<<1, 1024, 0, stream>>>(cnt, cursor, bnacc, N, E);
  k_prep<<<(E + 63)/64, 256, 0, stream>>>(nf, ei, sh, radial, W1, b1, cursor,
      uG, cabG, cvG, permG, E, NT);
  k_edge<<<256, 512, 0, stream>>>(w2t, b2, uG, cabG, cvG, ei, permG,
      kvt, carr, env, partU, msgs, logits_s, E, NT);
  k_agg<<<(N + 3)/4, 256, 0, stream>>>(msgs, logits_s, cursor, nf,
      Wout_s, Wout_v, Wg_s, Wg_v, xbuf, bnacc, N);
  k_out<<<(N*80 + 255)/256, 256, 0, stream>>>(xbuf, bnacc, bn_ws, bn_bs, bn_wv,
      (float*)d_out, N);
}

// Round 8
// 361.003 us; speedup vs baseline: 1.2711x; 1.0421x over previous
//
#include <hip/hip_runtime.h>
#include <math.h>

typedef __bf16 bf16x8 __attribute__((ext_vector_type(8)));
typedef __bf16 bf16x4 __attribute__((ext_vector_type(4)));
typedef float  f32x4  __attribute__((ext_vector_type(4)));
typedef float  f32x2  __attribute__((ext_vector_type(2)));
typedef unsigned long long u64x2 __attribute__((ext_vector_type(2)));

__device__ __forceinline__ float silu_f(float x){ return x / (1.f + __expf(-x)); }
__device__ __forceinline__ float sigm_f(float x){ return 1.f / (1.f + __expf(-x)); }

__device__ __forceinline__ float ntld_f(const float* p){
  return __builtin_nontemporal_load(p);
}
__device__ __forceinline__ float ntbf(const __bf16* p){
  unsigned short us = __builtin_nontemporal_load((const unsigned short*)p);
  union { unsigned u; float f; } cv; cv.u = ((unsigned)us) << 16;
  return cv.f;
}
__device__ __forceinline__ void nt_store_f(float* p, float v){
  __builtin_nontemporal_store(v, p);
}
__device__ __forceinline__ void nt_store_b8(__bf16* p, bf16x8 v){
  u64x2 u; __builtin_memcpy(&u, &v, 16);
  __builtin_nontemporal_store(u, (u64x2*)p);
}
__device__ __forceinline__ f32x2 b4lo(bf16x4 v){ f32x2 r; r[0]=(float)v[0]; r[1]=(float)v[1]; return r; }
__device__ __forceinline__ f32x2 b4hi(bf16x4 v){ f32x2 r; r[0]=(float)v[2]; r[1]=(float)v[3]; return r; }

// Block ranges: [0,nbPrep) W2->bf16 transpose; [nbPrep,+nbHist) dst histogram;
// rest: per-node attention vectors kv[n]=Wk@(nf@Wq+bq), c[n]=(nf@Wq+bq).bk
__global__ void __launch_bounds__(256) k_setup(const float* __restrict__ W2,
    __bf16* __restrict__ W2t, const int* __restrict__ ei, int* __restrict__ cnt,
    const float* __restrict__ nf, const float* __restrict__ Wq,
    const float* __restrict__ bq, const float* __restrict__ Wk,
    const float* __restrict__ bk, float* __restrict__ kvt, float* __restrict__ carr,
    int nbPrep, int nbHist, int N, int E){
  int b = blockIdx.x, t = threadIdx.x;
  if (b < nbPrep){
    int gid = b*256 + t;   // 163840 total
    int h = gid / 2560;
    int col = gid - h*2560;
    W2t[(size_t)(h>>5)*81920 + col*32 + (h&31)] = (__bf16)ntld_f(&W2[gid]);
    return;
  }
  if (b < nbPrep + nbHist){
    int e = (b - nbPrep)*256 + t;
    if (e < E) atomicAdd(&cnt[ei[E+e]], 1);
    return;
  }
  __shared__ float M[32][33];
  __shared__ float mb[32];
  __shared__ float nfl[64][33];
  __shared__ float bqbk_s;
  const int n0 = (b - nbPrep - nbHist)*64;
  for (int idx = t; idx < 1024; idx += 256){
    int s = idx >> 5, i = idx & 31;
    float acc = 0.f;
    #pragma unroll
    for (int j = 0; j < 8; ++j) acc += Wq[s*8+j]*Wk[i*8+j];
    M[s][i] = acc;
  }
  if (t < 32){
    float acc = 0.f;
    #pragma unroll
    for (int j = 0; j < 8; ++j) acc += Wq[t*8+j]*bk[j];
    mb[t] = acc;
  }
  if (t == 0){
    float acc = 0.f;
    #pragma unroll
    for (int j = 0; j < 8; ++j) acc += bq[j]*bk[j];
    bqbk_s = acc;
  }
  for (int idx = t; idx < 2048; idx += 256){
    int nl = idx >> 5, s = idx & 31;
    int n = n0 + nl;
    nfl[nl][s] = (n < N) ? nf[(size_t)n*80 + s] : 0.f;
  }
  __syncthreads();
  for (int idx = t; idx < 2048; idx += 256){
    int nl = idx >> 5, i = idx & 31;
    int n = n0 + nl;
    if (n < N){
      float acc = 0.f;
      #pragma unroll 8
      for (int s = 0; s < 32; ++s) acc += nfl[nl][s]*M[s][i];
      kvt[(size_t)n*32 + i] = acc;
    }
  }
  if (t < 64){
    int n = n0 + t;
    if (n < N){
      float acc = bqbk_s;
      #pragma unroll 8
      for (int s = 0; s < 32; ++s) acc += nfl[t][s]*mb[s];
      carr[n] = acc;
    }
  }
}

__global__ void __launch_bounds__(1024) k_scan(const int* __restrict__ cnt,
    int* __restrict__ cursor, float* __restrict__ bnacc, int N, int E){
  __shared__ int part[1024];
  int t = threadIdx.x;
  if (t < 80) bnacc[t] = 0.f;
  int chunk = (N + 1023) >> 10;
  int lo = t*chunk, hi = min(lo+chunk, N);
  int s = 0;
  for (int i = lo; i < hi; ++i) s += cnt[i];
  part[t] = s;
  __syncthreads();
  for (int off = 1; off < 1024; off <<= 1){
    int v = (t >= off) ? part[t-off] : 0;
    __syncthreads();
    part[t] += v;
    __syncthreads();
  }
  int base = (t == 0) ? 0 : part[t-1];
  for (int i = lo; i < hi; ++i){
    cursor[i] = base;
    base += cnt[i];
  }
}

// Per-edge precompute: u = silu(radial@W1+b1) (bf16, MFMA-A tiled layout),
// coefficient tables cAB/cV (bf16, tile-transposed), CSR perm. 64 edges/block.
__global__ void __launch_bounds__(256) k_prep(
    const float* __restrict__ nf, const int* __restrict__ ei,
    const float* __restrict__ sh, const float* __restrict__ radial,
    const float* __restrict__ W1, const float* __restrict__ b1,
    int* __restrict__ cursor,
    __bf16* __restrict__ uG, __bf16* __restrict__ cabG, __bf16* __restrict__ cvG,
    int* __restrict__ permG, int E, int NT)
{
  __shared__ float featT[80][65];
  __shared__ float radl[64][17];
  __shared__ float shlT[4][64];
  __shared__ float w1l[1024];
  __shared__ float b1l[64];
  __shared__ __align__(16) __bf16 u_l[64][72];
  __shared__ __align__(16) __bf16 cab_l[48][64];
  __shared__ __align__(16) __bf16 cv_l[64][3][64];
  __shared__ int src_l[64];

  const int t = threadIdx.x;
  const int e0 = blockIdx.x*64;
  const int tg0 = blockIdx.x*4;

  if (t < 64){
    int ee = e0 + t;
    if (ee < E){
      src_l[t] = ei[ee];
      permG[ee] = atomicAdd(&cursor[ei[(size_t)E+ee]], 1);
    } else src_l[t] = ei[E-1];
    b1l[t] = b1[t];
  }
  {
    int e = t >> 2, c = t & 3;
    int ec = min(e0+e, E-1);
    shlT[c][e] = ntld_f(&sh[(size_t)ec*4+c]);
  }
  for (int i = t; i < 1024; i += 256){
    int e = i >> 4, r = i & 15;
    int ec = min(e0+e, E-1);
    radl[e][r] = ntld_f(&radial[(size_t)ec*16+r]);
  }
  *(float4*)&w1l[t*4] = ((const float4*)W1)[t];
  __syncthreads();

  for (int i = t; i < 5120; i += 256){
    int e = i / 80, idx = i - e*80;
    featT[idx][e] = nf[(size_t)src_l[e]*80 + idx];
  }
  for (int i = t; i < 4096; i += 256){
    int e = i & 63, h = i >> 6;
    float acc = b1l[h];
    #pragma unroll
    for (int r = 0; r < 16; ++r) acc += radl[e][r]*w1l[r*64+h];
    u_l[e][h] = (__bf16)silu_f(acc);
  }
  __syncthreads();

  const float inv_s3 = 0.57735026918962576f;
  const float inv_s2 = 0.70710678118654752f;
  const float a0 = 0.14433756729740643f;  // 1/sqrt(48)
  const float a1 = 0.125f;                // 1/sqrt(64)

  for (int i = t; i < 3072; i += 256){
    int r = i >> 6, e = i & 63;
    float val;
    if (r < 32) val = a0 * shlT[0][e] * featT[r][e];
    else {
      int v = r - 32;
      float dot = (featT[32+v*3][e]*shlT[1][e] + featT[33+v*3][e]*shlT[2][e]
                 + featT[34+v*3][e]*shlT[3][e]) * inv_s3;
      val = a0 * dot;
    }
    cab_l[r][e] = (__bf16)val;
  }
  for (int i = t; i < 12288; i += 256){
    int e = i & 63, r = (i >> 6) & 63, c = i >> 12;
    float val;
    if (r < 32) val = a1 * shlT[1+c][e] * featT[r][e];
    else if (r < 48){
      int v = r - 32;
      val = a1 * shlT[0][e] * featT[32+v*3+c][e];
    } else {
      int v = r - 48;
      int c1 = c+1; if (c1 > 2) c1 -= 3;
      int c2 = c+2; if (c2 > 2) c2 -= 3;
      val = a1 * inv_s2 * (featT[32+v*3+c1][e]*shlT[1+c2][e]
                         - featT[32+v*3+c2][e]*shlT[1+c1][e]);
    }
    cv_l[r][c][e] = (__bf16)val;
  }
  __syncthreads();

  // ---- tiled outputs (16 edges per tile; tile layouts match k_edge lanes)
  // uG[tile]: [k8][e][j8] bf16 (2048 B)
  for (int i = t; i < 512; i += 256){
    int tl = i >> 7, rem = i & 127, k8 = rem >> 4, e = rem & 15;
    if (tg0 + tl < NT){
      bf16x8 v = *(const bf16x8*)&u_l[tl*16 + e][k8*8];
      *(bf16x8*)((char*)uG + (size_t)(tg0+tl)*2048 + k8*256 + e*16) = v;
    }
  }
  // cabG[tile]: [r48][e16] bf16 (1536 B)
  for (int i = t; i < 384; i += 256){
    int tl = i / 96, rem = i - tl*96, r = rem >> 1, h = rem & 1;
    if (tg0 + tl < NT){
      bf16x8 v = *(const bf16x8*)&cab_l[r][tl*16 + h*8];
      *(bf16x8*)((char*)cabG + (size_t)(tg0+tl)*1536 + r*32 + h*16) = v;
    }
  }
  // cvG[tile]: [r64][c3][e16] bf16 (6144 B)
  for (int i = t; i < 1536; i += 256){
    int tl = i / 384, rem = i - tl*384, r = rem / 6, rem2 = rem - r*6,
        c = rem2 >> 1, h = rem2 & 1;
    if (tg0 + tl < NT){
      bf16x8 v = *(const bf16x8*)&cv_l[r][c][tl*16 + h*8];
      *(bf16x8*)((char*)cvG + (size_t)(tg0+tl)*6144 + r*96 + c*32 + h*16) = v;
    }
  }
}

// Panel stored quad-major: frag(col,quad) at itl*2048 + half*1024 + quad*256
// + col*16 -> a wave's 64 ds_read_b128 lanes hit 64 consecutive 16B chunks
// (conflict-free), vs col-major 64B stride (2 banks, ~16x serialization).
#define LOAD_PANEL(BASE_IT, NITS) do {                                         \
    for (int idx = t; idx < (NITS)*128; idx += 512){                           \
      int itl_ = idx >> 7, rem_ = idx & 127, half_ = rem_ >> 6, r6_ = rem_ & 63;\
      int col_ = r6_ >> 2, quad_ = r6_ & 3;                                    \
      *(float4*)(panel + itl_*2048 + half_*1024 + quad_*256 + col_*16) =       \
        *(const float4*)(w2b + half_*163840 + (size_t)((BASE_IT)+itl_)*1024    \
                         + col_*64 + quad_*16);                                \
    }                                                                          \
    for (int i = t; i < (NITS)*16; i += 512) b2l[i] = b2[(BASE_IT)*16 + i];    \
  } while(0)

// 2 tiles (32 edges) per wave per pass: each panel ds_read feeds 4 MFMAs.
// Pairs (2*wgid, 2*wgid+1), outer stride 4096 -> max 96 itl/wave/phase.
#define S_PHASE(SECOND) do {                                                   \
  for (int outer = 0; outer < 2; ++outer){                                     \
    const int tgA = 2*wgid + outer*4096;                                       \
    if (tgA >= NT) break;                                                      \
    const int tgB = tgA + 1;                                                   \
    const bool hB = (tgB < NT);                                                \
    const int tgBc = hB ? tgB : tgA;                                           \
    bf16x8 aA0 = *(const bf16x8*)(uGb + (size_t)tgA*2048 + uOff);              \
    bf16x8 aA1 = *(const bf16x8*)(uGb + (size_t)tgA*2048 + 1024 + uOff);       \
    bf16x8 aB0 = *(const bf16x8*)(uGb + (size_t)tgBc*2048 + uOff);             \
    bf16x8 aB1 = *(const bf16x8*)(uGb + (size_t)tgBc*2048 + 1024 + uOff);      \
    {                                                                          \
      bf16x8 cA16 = *(const bf16x8*)(cabGb + (size_t)tgA*1536 + lane*16);      \
      bf16x4 cA8  = *(const bf16x4*)(cabGb + (size_t)tgA*1536 + 1024 + lane*8);\
      bf16x8 cB16 = *(const bf16x8*)(cabGb + (size_t)tgBc*1536 + lane*16);     \
      bf16x4 cB8  = *(const bf16x4*)(cabGb + (size_t)tgBc*1536 + 1024 + lane*8);\
      *(bf16x8*)(myCab + lane*16) = cA16;                                      \
      *(bf16x4*)(myCab + 1024 + lane*8) = cA8;                                 \
      *(bf16x8*)(myCab + 1536 + lane*16) = cB16;                               \
      *(bf16x4*)(myCab + 2560 + lane*8) = cB8;                                 \
    }                                                                          \
    f32x2 sA0lo={0,0}, sA0hi={0,0}, sA1lo={0,0}, sA1hi={0,0};                  \
    f32x2 sB0lo={0,0}, sB0hi={0,0}, sB1lo={0,0}, sB1hi={0,0};                  \
    if (SECOND){                                                               \
      f32x4 p;                                                                 \
      p = *(const f32x4*)(partU + (size_t)tgA*768 + lane*8);                   \
      sA0lo[0]=p[0]; sA0lo[1]=p[1]; sA0hi[0]=p[2]; sA0hi[1]=p[3];              \
      p = *(const f32x4*)(partU + (size_t)tgA*768 + lane*8 + 4);               \
      sA1lo[0]=p[0]; sA1lo[1]=p[1]; sA1hi[0]=p[2]; sA1hi[1]=p[3];              \
      p = *(const f32x4*)(partU + (size_t)tgBc*768 + lane*8);                  \
      sB0lo[0]=p[0]; sB0lo[1]=p[1]; sB0hi[0]=p[2]; sB0hi[1]=p[3];              \
      p = *(const f32x4*)(partU + (size_t)tgBc*768 + lane*8 + 4);              \
      sB1lo[0]=p[0]; sB1lo[1]=p[1]; sB1hi[0]=p[2]; sB1hi[1]=p[3];              \
    }                                                                          \
    _Pragma("unroll 4")                                                        \
    for (int itl = 0; itl < 48; ++itl){                                        \
      bf16x8 B0 = *(const bf16x8*)(panel + itl*2048 + laneOff);                \
      bf16x8 B1 = *(const bf16x8*)(panel + itl*2048 + 1024 + laneOff);         \
      f32x4 dA; dA[0]=0;dA[1]=0;dA[2]=0;dA[3]=0; f32x4 dB = dA;                \
      dA = __builtin_amdgcn_mfma_f32_16x16x32_bf16(aA0, B0, dA, 0,0,0);        \
      dB = __builtin_amdgcn_mfma_f32_16x16x32_bf16(aB0, B0, dB, 0,0,0);        \
      dA = __builtin_amdgcn_mfma_f32_16x16x32_bf16(aA1, B1, dA, 0,0,0);        \
      dB = __builtin_amdgcn_mfma_f32_16x16x32_bf16(aB1, B1, dB, 0,0,0);        \
      const float bias = b2l[itl*16 + nlo];                                    \
      f32x2 bb; bb[0]=bias; bb[1]=bias;                                        \
      f32x2 dAlo = __builtin_shufflevector(dA,dA,0,1) + bb;                    \
      f32x2 dAhi = __builtin_shufflevector(dA,dA,2,3) + bb;                    \
      f32x2 dBlo = __builtin_shufflevector(dB,dB,0,1) + bb;                    \
      f32x2 dBhi = __builtin_shufflevector(dB,dB,2,3) + bb;                    \
      const int r = (SECOND)*24 + (itl>>1);                                    \
      bf16x4 cA = *(const bf16x4*)(myCab + r*32 + quad*8);                     \
      bf16x4 cB = *(const bf16x4*)(myCab + 1536 + r*32 + quad*8);              \
      if (itl & 1){                                                            \
        sA1lo += b4lo(cA)*dAlo; sA1hi += b4hi(cA)*dAhi;                        \
        sB1lo += b4lo(cB)*dBlo; sB1hi += b4hi(cB)*dBhi;                        \
      } else {                                                                 \
        sA0lo += b4lo(cA)*dAlo; sA0hi += b4hi(cA)*dAhi;                        \
        sB0lo += b4lo(cB)*dBlo; sB0hi += b4hi(cB)*dBhi;                        \
      }                                                                        \
    }                                                                          \
    if (!(SECOND)){                                                            \
      f32x4 P;                                                                 \
      P[0]=sA0lo[0]; P[1]=sA0lo[1]; P[2]=sA0hi[0]; P[3]=sA0hi[1];              \
      *(f32x4*)(partU + (size_t)tgA*768 + lane*8) = P;                         \
      P[0]=sA1lo[0]; P[1]=sA1lo[1]; P[2]=sA1hi[0]; P[3]=sA1hi[1];              \
      *(f32x4*)(partU + (size_t)tgA*768 + lane*8 + 4) = P;                     \
      if (hB){                                                                 \
        P[0]=sB0lo[0]; P[1]=sB0lo[1]; P[2]=sB0hi[0]; P[3]=sB0hi[1];            \
        *(f32x4*)(partU + (size_t)tgB*768 + lane*8) = P;                       \
        P[0]=sB1lo[0]; P[1]=sB1lo[1]; P[2]=sB1hi[0]; P[3]=sB1hi[1];            \
        *(f32x4*)(partU + (size_t)tgB*768 + lane*8 + 4) = P;                   \
      }                                                                        \
    } else {                                                                   \
      const int eb = quad*4;                                                   \
      S_FLUSH(tgA, sA0lo, sA0hi, sA1lo, sA1hi);                                \
      if (hB){ S_FLUSH(tgB, sB0lo, sB0hi, sB1lo, sB1hi); }                     \
    }                                                                          \
  }                                                                            \
} while(0)

#define S_FLUSH(TG, S0LO, S0HI, S1LO, S1HI) do {                               \
      myOut[(eb+0)*56 + nlo] = S0LO[0];                                        \
      myOut[(eb+1)*56 + nlo] = S0LO[1];                                        \
      myOut[(eb+2)*56 + nlo] = S0HI[0];                                        \
      myOut[(eb+3)*56 + nlo] = S0HI[1];                                        \
      myOut[(eb+0)*56 + 16+nlo] = S1LO[0];                                     \
      myOut[(eb+1)*56 + 16+nlo] = S1LO[1];                                     \
      myOut[(eb+2)*56 + 16+nlo] = S1HI[0];                                     \
      myOut[(eb+3)*56 + 16+nlo] = S1HI[1];                                     \
      const int e0e = (TG)*16;                                                 \
      { int e = lane>>2, seg = lane&3, eg = e0e + e;                           \
        if (eg < E){                                                           \
          f32x4 m0 = *(const f32x4*)&myOut[e*56 + seg*8];                      \
          f32x4 m1 = *(const f32x4*)&myOut[e*56 + seg*8 + 4];                  \
          bf16x8 o; o[0]=(__bf16)m0[0]; o[1]=(__bf16)m0[1];                    \
          o[2]=(__bf16)m0[2]; o[3]=(__bf16)m0[3]; o[4]=(__bf16)m1[0];          \
          o[5]=(__bf16)m1[1]; o[6]=(__bf16)m1[2]; o[7]=(__bf16)m1[3];          \
          nt_store_b8(msgs + (size_t)permG[eg]*80 + seg*8, o);                 \
        } }                                                                    \
      for (int r8 = 0; r8 < 2; ++r8){                                          \
        int e = r8*8 + (lane>>3), kq = lane&7, eg = e0e + e;                   \
        f32x4 ms = *(const f32x4*)&myOut[e*56 + kq*4];                         \
        int dn = ei[(size_t)E + min(eg, E-1)];                                 \
        const float* kvp = kvt + (size_t)dn*32 + kq*4;                         \
        float part = ms[0]*kvp[0]+ms[1]*kvp[1]+ms[2]*kvp[2]+ms[3]*kvp[3];      \
        part += __shfl_xor(part, 1);                                           \
        part += __shfl_xor(part, 2);                                           \
        part += __shfl_xor(part, 4);                                           \
        if (kq == 0 && eg < E){                                                \
          float lg = (part + carr[dn]) * 0.35355339059327373f                  \
                   + logf(ntld_f(&env[eg]) + 1e-8f);                           \
          nt_store_f(&logits_s[permG[eg]], lg);                                \
        } }                                                                    \
  } while(0)

#define V_FLUSH(TG, V0LO, V0HI, V1LO, V1HI, V2LO, V2HI) do {                   \
      const int cb2 = nlo*3;                                                   \
      myOut[(eb+0)*56 + cb2+0] = V0LO[0];                                      \
      myOut[(eb+1)*56 + cb2+0] = V0LO[1];                                      \
      myOut[(eb+2)*56 + cb2+0] = V0HI[0];                                      \
      myOut[(eb+3)*56 + cb2+0] = V0HI[1];                                      \
      myOut[(eb+0)*56 + cb2+1] = V1LO[0];                                      \
      myOut[(eb+1)*56 + cb2+1] = V1LO[1];                                      \
      myOut[(eb+2)*56 + cb2+1] = V1HI[0];                                      \
      myOut[(eb+3)*56 + cb2+1] = V1HI[1];                                      \
      myOut[(eb+0)*56 + cb2+2] = V2LO[0];                                      \
      myOut[(eb+1)*56 + cb2+2] = V2LO[1];                                      \
      myOut[(eb+2)*56 + cb2+2] = V2HI[0];                                      \
      myOut[(eb+3)*56 + cb2+2] = V2HI[1];                                      \
      const int e0e = (TG)*16;                                                 \
      for (int i = lane; i < 96; i += 64){                                     \
        int e = i/6, seg = i - (i/6)*6, eg = e0e + e;                          \
        if (eg < E){                                                           \
          f32x4 m0 = *(const f32x4*)&myOut[e*56 + seg*8];                      \
          f32x4 m1 = *(const f32x4*)&myOut[e*56 + seg*8 + 4];                  \
          bf16x8 o; o[0]=(__bf16)m0[0]; o[1]=(__bf16)m0[1];                    \
          o[2]=(__bf16)m0[2]; o[3]=(__bf16)m0[3]; o[4]=(__bf16)m1[0];          \
          o[5]=(__bf16)m1[1]; o[6]=(__bf16)m1[2]; o[7]=(__bf16)m1[3];          \
          nt_store_b8(msgs + (size_t)permG[eg]*80 + 32 + seg*8, o);            \
        } }                                                                    \
  } while(0)

#define V_PHASE(SECOND) do {                                                   \
  for (int outer = 0; outer < 2; ++outer){                                     \
    const int tgA = 2*wgid + outer*4096;                                       \
    if (tgA >= NT) break;                                                      \
    const int tgB = tgA + 1;                                                   \
    const bool hB = (tgB < NT);                                                \
    const int tgBc = hB ? tgB : tgA;                                           \
    bf16x8 aA0 = *(const bf16x8*)(uGb + (size_t)tgA*2048 + uOff);              \
    bf16x8 aA1 = *(const bf16x8*)(uGb + (size_t)tgA*2048 + 1024 + uOff);       \
    bf16x8 aB0 = *(const bf16x8*)(uGb + (size_t)tgBc*2048 + uOff);             \
    bf16x8 aB1 = *(const bf16x8*)(uGb + (size_t)tgBc*2048 + 1024 + uOff);      \
    {                                                                          \
      bf16x8 c0 = *(const bf16x8*)(cvGb + (size_t)tgA*6144 + (SECOND)*3072 + lane*48);\
      bf16x8 c1 = *(const bf16x8*)(cvGb + (size_t)tgA*6144 + (SECOND)*3072 + lane*48 + 16);\
      bf16x8 c2 = *(const bf16x8*)(cvGb + (size_t)tgA*6144 + (SECOND)*3072 + lane*48 + 32);\
      *(bf16x8*)(myCab + lane*48)      = c0;                                   \
      *(bf16x8*)(myCab + lane*48 + 16) = c1;                                   \
      *(bf16x8*)(myCab + lane*48 + 32) = c2;                                   \
      c0 = *(const bf16x8*)(cvGb + (size_t)tgBc*6144 + (SECOND)*3072 + lane*48);\
      c1 = *(const bf16x8*)(cvGb + (size_t)tgBc*6144 + (SECOND)*3072 + lane*48 + 16);\
      c2 = *(const bf16x8*)(cvGb + (size_t)tgBc*6144 + (SECOND)*3072 + lane*48 + 32);\
      *(bf16x8*)(myCab + 3072 + lane*48)      = c0;                            \
      *(bf16x8*)(myCab + 3072 + lane*48 + 16) = c1;                            \
      *(bf16x8*)(myCab + 3072 + lane*48 + 32) = c2;                            \
    }                                                                          \
    f32x2 vA0lo={0,0}, vA0hi={0,0}, vA1lo={0,0}, vA1hi={0,0}, vA2lo={0,0}, vA2hi={0,0};\
    f32x2 vB0lo={0,0}, vB0hi={0,0}, vB1lo={0,0}, vB1hi={0,0}, vB2lo={0,0}, vB2hi={0,0};\
    if (SECOND){                                                               \
      f32x4 p;                                                                 \
      p = *(const f32x4*)(partU + (size_t)tgA*768 + lane*12);                  \
      vA0lo[0]=p[0]; vA0lo[1]=p[1]; vA0hi[0]=p[2]; vA0hi[1]=p[3];              \
      p = *(const f32x4*)(partU + (size_t)tgA*768 + lane*12 + 4);              \
      vA1lo[0]=p[0]; vA1lo[1]=p[1]; vA1hi[0]=p[2]; vA1hi[1]=p[3];              \
      p = *(const f32x4*)(partU + (size_t)tgA*768 + lane*12 + 8);              \
      vA2lo[0]=p[0]; vA2lo[1]=p[1]; vA2hi[0]=p[2]; vA2hi[1]=p[3];              \
      p = *(const f32x4*)(partU + (size_t)tgBc*768 + lane*12);                 \
      vB0lo[0]=p[0]; vB0lo[1]=p[1]; vB0hi[0]=p[2]; vB0hi[1]=p[3];              \
      p = *(const f32x4*)(partU + (size_t)tgBc*768 + lane*12 + 4);             \
      vB1lo[0]=p[0]; vB1lo[1]=p[1]; vB1hi[0]=p[2]; vB1hi[1]=p[3];              \
      p = *(const f32x4*)(partU + (size_t)tgBc*768 + lane*12 + 8);             \
      vB2lo[0]=p[0]; vB2lo[1]=p[1]; vB2hi[0]=p[2]; vB2hi[1]=p[3];              \
    }                                                                          \
    _Pragma("unroll 4")                                                        \
    for (int itl = 0; itl < 32; ++itl){                                        \
      bf16x8 B0 = *(const bf16x8*)(panel + itl*2048 + laneOff);                \
      bf16x8 B1 = *(const bf16x8*)(panel + itl*2048 + 1024 + laneOff);         \
      f32x4 dA; dA[0]=0;dA[1]=0;dA[2]=0;dA[3]=0; f32x4 dB = dA;                \
      dA = __builtin_amdgcn_mfma_f32_16x16x32_bf16(aA0, B0, dA, 0,0,0);        \
      dB = __builtin_amdgcn_mfma_f32_16x16x32_bf16(aB0, B0, dB, 0,0,0);        \
      dA = __builtin_amdgcn_mfma_f32_16x16x32_bf16(aA1, B1, dA, 0,0,0);        \
      dB = __builtin_amdgcn_mfma_f32_16x16x32_bf16(aB1, B1, dB, 0,0,0);        \
      const float bias = b2l[itl*16 + nlo];                                    \
      f32x2 bb; bb[0]=bias; bb[1]=bias;                                        \
      f32x2 dAlo = __builtin_shufflevector(dA,dA,0,1) + bb;                    \
      f32x2 dAhi = __builtin_shufflevector(dA,dA,2,3) + bb;                    \
      f32x2 dBlo = __builtin_shufflevector(dB,dB,0,1) + bb;                    \
      f32x2 dBhi = __builtin_shufflevector(dB,dB,2,3) + bb;                    \
      const char* cbA_ = myCab + itl*96;                                       \
      const char* cbB_ = myCab + 3072 + itl*96;                                \
      bf16x4 q0 = *(const bf16x4*)(cbA_ + quad*8);                             \
      bf16x4 q1 = *(const bf16x4*)(cbA_ + 32 + quad*8);                        \
      bf16x4 q2 = *(const bf16x4*)(cbA_ + 64 + quad*8);                        \
      vA0lo += b4lo(q0)*dAlo; vA0hi += b4hi(q0)*dAhi;                          \
      vA1lo += b4lo(q1)*dAlo; vA1hi += b4hi(q1)*dAhi;                          \
      vA2lo += b4lo(q2)*dAlo; vA2hi += b4hi(q2)*dAhi;                          \
      q0 = *(const bf16x4*)(cbB_ + quad*8);                                    \
      q1 = *(const bf16x4*)(cbB_ + 32 + quad*8);                               \
      q2 = *(const bf16x4*)(cbB_ + 64 + quad*8);                               \
      vB0lo += b4lo(q0)*dBlo; vB0hi += b4hi(q0)*dBhi;                          \
      vB1lo += b4lo(q1)*dBlo; vB1hi += b4hi(q1)*dBhi;                          \
      vB2lo += b4lo(q2)*dBlo; vB2hi += b4hi(q2)*dBhi;                          \
    }                                                                          \
    if (!(SECOND)){                                                            \
      f32x4 P;                                                                 \
      P[0]=vA0lo[0]; P[1]=vA0lo[1]; P[2]=vA0hi[0]; P[3]=vA0hi[1];              \
      *(f32x4*)(partU + (size_t)tgA*768 + lane*12) = P;                        \
      P[0]=vA1lo[0]; P[1]=vA1lo[1]; P[2]=vA1hi[0]; P[3]=vA1hi[1];              \
      *(f32x4*)(partU + (size_t)tgA*768 + lane*12 + 4) = P;                    \
      P[0]=vA2lo[0]; P[1]=vA2lo[1]; P[2]=vA2hi[0]; P[3]=vA2hi[1];              \
      *(f32x4*)(partU + (size_t)tgA*768 + lane*12 + 8) = P;                    \
      if (hB){                                                                 \
        P[0]=vB0lo[0]; P[1]=vB0lo[1]; P[2]=vB0hi[0]; P[3]=vB0hi[1];            \
        *(f32x4*)(partU + (size_t)tgB*768 + lane*12) = P;                      \
        P[0]=vB1lo[0]; P[1]=vB1lo[1]; P[2]=vB1hi[0]; P[3]=vB1hi[1];            \
        *(f32x4*)(partU + (size_t)tgB*768 + lane*12 + 4) = P;                  \
        P[0]=vB2lo[0]; P[1]=vB2lo[1]; P[2]=vB2hi[0]; P[3]=vB2hi[1];            \
        *(f32x4*)(partU + (size_t)tgB*768 + lane*12 + 8) = P;                  \
      }                                                                        \
    } else {                                                                   \
      const int eb = quad*4;                                                   \
      V_FLUSH(tgA, vA0lo, vA0hi, vA1lo, vA1hi, vA2lo, vA2hi);                  \
      if (hB){ V_FLUSH(tgB, vB0lo, vB0hi, vB1lo, vB1hi, vB2lo, vB2hi); }       \
    }                                                                          \
  }                                                                            \
} while(0)

// Persistent-panel edge kernel: 256 blocks x 512 threads (1 block/CU).
// 4 phases, each loads a W2t panel (<=96 KB) into LDS once (swizzled
// quad-major -> conflict-free ds_read_b128); waves grind 2-tile pairs
// against it (each panel read feeds 4 MFMAs). LDS ~147 KB.
__global__ void __launch_bounds__(512, 1) k_edge(
    const __bf16* __restrict__ W2t, const float* __restrict__ b2,
    const __bf16* __restrict__ uG, const __bf16* __restrict__ cabG,
    const __bf16* __restrict__ cvG, const int* __restrict__ ei,
    const int* __restrict__ permG, const float* __restrict__ kvt,
    const float* __restrict__ carr, const float* __restrict__ env,
    float* __restrict__ partU, __bf16* __restrict__ msgs,
    float* __restrict__ logits_s, int E, int NT)
{
  __shared__ __align__(16) char panel[98304];      // 48 its x 2048 B (swizzled)
  __shared__ __align__(16) char wstage[8][6144];   // per wave: coef stage / out alias
  __shared__ float b2l[768];

  const int t = threadIdx.x;
  const int lane = t & 63;
  const int wv   = t >> 6;
  const int quad = lane >> 4;
  const int nlo  = lane & 15;
  const int wgid = blockIdx.x*8 + wv;
  const int laneOff = quad*256 + nlo*16;  // panel B-fragment byte offset (swizzled)
  const int uOff    = quad*256 + nlo*16;  // u A-fragment byte offset
  char*  myCab = wstage[wv];
  float* myOut = (float*)wstage[wv];      // aliases coef stage (post-loop use only)
  const char* w2b   = (const char*)W2t;
  const char* uGb   = (const char*)uG;
  const char* cabGb = (const char*)cabG;
  const char* cvGb  = (const char*)cvG;

  LOAD_PANEL(0, 48);
  __syncthreads();
  S_PHASE(0);
  __syncthreads();
  LOAD_PANEL(48, 48);
  __syncthreads();
  S_PHASE(1);
  __syncthreads();
  LOAD_PANEL(96, 32);
  __syncthreads();
  V_PHASE(0);
  __syncthreads();
  LOAD_PANEL(128, 32);
  __syncthreads();
  V_PHASE(1);
}

// One wave per node: max pass, merged gather+den pass (bf16 msgs, NT loads),
// fused node matmuls + gate + residual + BN stats.
__global__ void __launch_bounds__(256) k_agg(
    const __bf16* __restrict__ msgs, const float* __restrict__ logits_s,
    const int* __restrict__ cursor, const float* __restrict__ nf,
    const float* __restrict__ Wout_s, const float* __restrict__ Wout_v,
    const float* __restrict__ Wg_s, const float* __restrict__ Wg_v,
    float* __restrict__ xbuf, float* __restrict__ bnacc, int N)
{
  __shared__ float aggl[4][80];
  __shared__ float t1[4][96];
  __shared__ float t2[4][96];
  __shared__ float bnl[80];
  const int t = threadIdx.x, l = t & 63, wv = t >> 6;
  const int n = blockIdx.x*4 + wv;
  const bool act = (n < N);
  const int nc = act ? n : (N-1);
  if (t < 80) bnl[t] = 0.f;

  const int r0 = (nc == 0) ? 0 : cursor[nc-1];
  const int r1 = cursor[nc];
  const int deg = act ? (r1 - r0) : 0;

  float mym = -3.4e38f;
  for (int i = l; i < deg; i += 64) mym = fmaxf(mym, logits_s[r0+i]);
  #pragma unroll
  for (int s = 32; s; s >>= 1) mym = fmaxf(mym, __shfl_xor(mym, s));
  float denp = 0.f, acc0 = 0.f, acc1 = 0.f;
  for (int c0 = 0; c0 < deg; c0 += 64){
    const int len = min(64, deg - c0);
    float ex = 0.f;
    if (l < len) ex = __expf(logits_s[r0+c0+l] - mym);
    denp += ex;
    for (int j0 = 0; j0 < len; j0 += 4){
      const int jn = len - j0;
      const __bf16* base = msgs + (size_t)(r0+c0+j0)*80;
      float v0=0,v1=0,v2=0,v3=0, w0=0,w1=0,w2=0,w3=0;
      float a0_=0,a1_=0,a2_=0,a3_=0;
      v0 = ntbf(&base[l]); if (l < 16) w0 = ntbf(&base[64+l]); a0_ = __shfl(ex, j0);
      if (jn > 1){ v1 = ntbf(&base[80+l]);  if (l < 16) w1 = ntbf(&base[144+l]); a1_ = __shfl(ex, j0+1); }
      if (jn > 2){ v2 = ntbf(&base[160+l]); if (l < 16) w2 = ntbf(&base[224+l]); a2_ = __shfl(ex, j0+2); }
      if (jn > 3){ v3 = ntbf(&base[240+l]); if (l < 16) w3 = ntbf(&base[304+l]); a3_ = __shfl(ex, j0+3); }
      acc0 += a0_*v0 + a1_*v1 + a2_*v2 + a3_*v3;
      if (l < 16) acc1 += a0_*w0 + a1_*w1 + a2_*w2 + a3_*w3;
    }
  }
  #pragma unroll
  for (int s = 32; s; s >>= 1) denp += __shfl_xor(denp, s);
  const float inv = 1.f/(denp + 1e-8f);
  aggl[wv][l] = acc0 * inv;
  if (l < 16) aggl[wv][64+l] = acc1 * inv;
  __syncthreads();

  const float* arow = &aggl[wv][0];
  const float iS = 0.17677669529663687f;  // 1/sqrt(32)
  const float iV = 0.25f;                 // 1/sqrt(16)
  for (int o = l; o < 80; o += 64){
    float val = 0.f;
    if (o < 32){
      for (int s = 0; s < 32; ++s) val += arow[s]*Wout_s[s*32+o];
      val *= iS;
    } else {
      int w = (o-32)/3, c = (o-32)-w*3;
      for (int v = 0; v < 16; ++v) val += arow[32+v*3+c]*Wout_v[v*16+w];
      val *= iV;
    }
    t1[wv][o] = val;
  }
  __syncthreads();
  for (int o = l; o < 96; o += 64){
    float val = 0.f;
    if (o < 48){
      for (int k = 0; k < 32; ++k) val += t1[wv][k]*Wg_s[k*48+o];
      val *= iS;
    } else {
      int w = (o-48)/3, c = (o-48)-w*3;
      for (int v = 0; v < 16; ++v) val += t1[wv][32+v*3+c]*Wg_v[v*16+w];
      val *= iV;
    }
    t2[wv][o] = val;
  }
  __syncthreads();
  for (int o = l; o < 80; o += 64){
    float x;
    if (o < 32){
      x = silu_f(t2[wv][o]) + nf[(size_t)nc*80+o];
      if (act){
        nt_store_f(&xbuf[(size_t)n*80+o], x);
        atomicAdd(&bnl[o], x);
        atomicAdd(&bnl[32+o], x*x);
      }
    } else {
      int w = (o-32)/3;
      x = sigm_f(t2[wv][32+w]) * t2[wv][48+(o-32)] + nf[(size_t)nc*80+o];
      if (act){
        nt_store_f(&xbuf[(size_t)n*80+o], x);
        atomicAdd(&bnl[64+w], x*x);
      }
    }
  }
  __syncthreads();
  if (t < 80) atomicAdd(&bnacc[t], bnl[t]);
}

__global__ void __launch_bounds__(256) k_out(const float* __restrict__ xbuf,
    const float* __restrict__ bnacc,
    const float* __restrict__ bn_ws, const float* __restrict__ bn_bs,
    const float* __restrict__ bn_wv, float* __restrict__ out, int N){
  __shared__ float coef[80];
  int t = threadIdx.x;
  float fN = (float)N;
  if (t < 32){
    float mean = bnacc[t]/fN;
    float var = bnacc[32+t]/fN - mean*mean;
    float cm = bn_ws[t]*rsqrtf(var + 1e-5f);
    coef[t] = cm;
    coef[32+t] = bn_bs[t] - mean*cm;
  } else if (t < 48){
    int v = t - 32;
    coef[64+v] = bn_wv[v]*rsqrtf(bnacc[64+v]/(3.f*fN) + 1e-5f);
  }
  __syncthreads();
  int i = blockIdx.x*256 + t;
  if (i >= N*80) return;
  int o = i - (i/80)*80;
  float x = ntld_f(&xbuf[i]);
  nt_store_f(&out[i], (o < 32) ? (x*coef[o] + coef[32+o]) : (x*coef[64+(o-32)/3]));
}

extern "C" void kernel_launch(void* const* d_in, const int* in_sizes, int n_in,
                              void* d_out, int out_size, void* d_ws, size_t ws_size,
                              hipStream_t stream) {
  const float* nf     = (const float*)d_in[0];
  const int*   ei     = (const int*)  d_in[1];
  const float* sh     = (const float*)d_in[2];
  const float* radial = (const float*)d_in[3];
  const float* env    = (const float*)d_in[4];
  const float* W1     = (const float*)d_in[5];
  const float* b1     = (const float*)d_in[6];
  const float* W2     = (const float*)d_in[7];
  const float* b2     = (const float*)d_in[8];
  const float* Wq     = (const float*)d_in[9];
  const float* bq     = (const float*)d_in[10];
  const float* Wk     = (const float*)d_in[11];
  const float* bk     = (const float*)d_in[12];
  const float* Wout_s = (const float*)d_in[13];
  const float* Wout_v = (const float*)d_in[14];
  const float* Wg_s   = (const float*)d_in[15];
  const float* Wg_v   = (const float*)d_in[16];
  const float* bn_ws  = (const float*)d_in[17];
  const float* bn_bs  = (const float*)d_in[18];
  const float* bn_wv  = (const float*)d_in[19];

  const int E = in_sizes[4];
  const int N = in_sizes[0] / 80;
  const int NT = (E + 15)/16;

  float* ws = (float*)d_ws;
  size_t off = 0;
  __bf16* w2t    = (__bf16*)(ws + off); off += 81920;          // 320 KB bf16
  __bf16* msgs   = (__bf16*)(ws + off); off += (size_t)E*40;   // E*80 bf16
  float* logits_s= ws + off; off += E;
  int* cnt       = (int*)(ws + off); off += N;
  int* cursor    = (int*)(ws + off); off += N;
  float* xbuf    = ws + off; off += (size_t)N*80;
  float* bnacc   = ws + off; off += 80;
  float* kvt     = ws + off; off += (size_t)N*32;
  float* carr    = ws + off; off += N;
  int* permG     = (int*)(ws + off); off += E;
  __bf16* uG     = (__bf16*)(ws + off); off += (size_t)NT*512;   // NT*2048 B
  __bf16* cabG   = (__bf16*)(ws + off); off += (size_t)NT*384;   // NT*1536 B
  __bf16* cvG    = (__bf16*)(ws + off); off += (size_t)NT*1536;  // NT*6144 B
  float* partU   = ws + off; off += (size_t)NT*768;              // NT*3072 B

  hipMemsetAsync(cnt, 0, (size_t)N*sizeof(int), stream);

  const int nbPrep = 640;                 // 163840/256
  const int nbHist = (E + 255)/256;
  const int nbKv   = (N + 63)/64;
  k_setup<<<nbPrep + nbHist + nbKv, 256, 0, stream>>>(W2, w2t, ei, cnt,
      nf, Wq, bq, Wk, bk, kvt, carr, nbPrep, nbHist, N, E);
  k_scan<<<1, 1024, 0, stream>>>(cnt, cursor, bnacc, N, E);
  k_prep<<<(E + 63)/64, 256, 0, stream>>>(nf, ei, sh, radial, W1, b1, cursor,
      uG, cabG, cvG, permG, E, NT);
  k_edge<<<256, 512, 0, stream>>>(w2t, b2, uG, cabG, cvG, ei, permG,
      kvt, carr, env, partU, msgs, logits_s, E, NT);
  k_agg<<<(N + 3)/4, 256, 0, stream>>>(msgs, logits_s, cursor, nf,
      Wout_s, Wout_v, Wg_s, Wg_v, xbuf, bnacc, N);
  k_out<<<(N*80 + 255)/256, 256, 0, stream>>>(xbuf, bnacc, bn_ws, bn_bs, bn_wv,
      (float*)d_out, N);
}